// Round 6
// baseline (1499.041 us; speedup 1.0000x reference)
//
#include <hip/hip_runtime.h>

#define DEV __device__ __forceinline__
typedef unsigned short u16;
typedef unsigned int u32;
typedef __bf16 bf16x8 __attribute__((ext_vector_type(8)));
typedef float f32x4 __attribute__((ext_vector_type(4)));

static constexpr int B = 8192, T = 90, F = 7, H = 128, NOUT = 30;

DEV float fexp2(float x) { return __builtin_amdgcn_exp2f(x); }
DEV float frcp(float x) { return __builtin_amdgcn_rcpf(x); }
DEV float frsq(float x) { return __builtin_amdgcn_rsqf(x); }
DEV float sigm(float x) { return frcp(1.f + fexp2(-1.44269504088896341f * x)); }
DEV u16 f2bfbits(float f) { __bf16 b = (__bf16)f; return __builtin_bit_cast(u16, b); }
DEV float bfbits2f(u32 u) { return __builtin_bit_cast(float, u << 16); }
DEV u32 pk2(float a, float b) { return (u32)f2bfbits(a) | ((u32)f2bfbits(b) << 16); }

DEV float wave_sum(float v) {
#pragma unroll
    for (int m = 32; m; m >>= 1) v += __shfl_xor(v, m, 64);
    return v;
}

// ---------------------------------------------------------------------------
// prep_aux: one 512-thread block. (unchanged)
// ---------------------------------------------------------------------------
__global__ __launch_bounds__(512) void prep_aux(
    const float* __restrict__ W_in, const float* __restrict__ b_in,
    const float* __restrict__ g_in, const float* __restrict__ be_in,
    const float* __restrict__ Wih0, float* __restrict__ aux, u16* __restrict__ Uhat) {
    const int tid = threadIdx.x;
    if (tid < 7) {
        float sm = 0.f, sp = 0.f;
        for (int h = 0; h < 128; ++h) { const float w = W_in[h * 7 + tid]; sm += w; sp += w * b_in[h]; }
        aux[tid] = sm * (1.f / 128.f); aux[64 + tid] = sp * (1.f / 128.f);
    } else if (tid < 56) {
        const int cd = tid - 7, cc = cd / 7, dd = cd % 7;
        float s = 0.f;
        for (int h = 0; h < 128; ++h) s += W_in[h * 7 + cc] * W_in[h * 7 + dd];
        aux[8 + cd] = s * (1.f / 128.f);
    } else if (tid == 56) {
        float s = 0.f; for (int h = 0; h < 128; ++h) s += b_in[h];
        aux[7] = s * (1.f / 128.f);
    } else if (tid == 57) {
        float s = 0.f; for (int h = 0; h < 128; ++h) s += b_in[h] * b_in[h];
        aux[72] = s * (1.f / 128.f);
    }
    float acc[10];
#pragma unroll
    for (int i = 0; i < 10; ++i) acc[i] = 0.f;
    const float* wr = Wih0 + (long)tid * 128;
    for (int h = 0; h < 128; ++h) {
        const float wv = wr[h], wg = wv * g_in[h];
#pragma unroll
        for (int cc = 0; cc < 7; ++cc) acc[cc] += wg * W_in[h * 7 + cc];
        acc[7] += wg * b_in[h]; acc[8] += wg; acc[9] += wv * be_in[h];
    }
    u16* dst = Uhat + tid * 32;
#pragma unroll
    for (int cc = 0; cc < 10; ++cc) dst[cc] = f2bfbits(acc[cc]);
#pragma unroll
    for (int cc = 10; cc < 32; ++cc) dst[cc] = 0;
}

// ---------------------------------------------------------------------------
// prep_stats (unchanged)
// ---------------------------------------------------------------------------
__global__ __launch_bounds__(256) void prep_stats(
    const float* __restrict__ x, const float* __restrict__ aux,
    float2* __restrict__ stats) {
    __shared__ float sa[80];
    const int tid = threadIdx.x;
    if (tid < 80) sa[tid] = aux[tid];
    __syncthreads();
    const long idx = (long)blockIdx.x * 256 + tid;
    const float* xr = x + idx * 7;
    float xv[7];
#pragma unroll
    for (int cc = 0; cc < 7; ++cc) xv[cc] = xr[cc];
    float mu = sa[7];
#pragma unroll
    for (int cc = 0; cc < 7; ++cc) mu += sa[cc] * xv[cc];
    float q = sa[72];
#pragma unroll
    for (int cc = 0; cc < 7; ++cc) {
        float tacc = 2.f * sa[64 + cc];
#pragma unroll
        for (int dd = 0; dd < 7; ++dd) tacc += sa[8 + cc * 7 + dd] * xv[dd];
        q += xv[cc] * tacc;
    }
    const float rstd = frsq(q - mu * mu + 1e-5f);
    stats[idx] = make_float2(rstd, -rstd * mu);
}

// Gate math for one element r: consumes acc[g][r] g=0..3, carries c, writes
// h bf16 to PTR[HWB + r*8].
#define GATE_E(ACC, CARR, PTR, HWB, R, B0, B1, B2, B3)                                  \
    {                                                                                   \
        const float xi_ = ACC[0][R] + (B0);                                             \
        const float xf_ = ACC[1][R] + (B1);                                             \
        const float xg_ = ACC[2][R] + (B2);                                             \
        const float xo_ = ACC[3][R] + (B3);                                             \
        const float tg_ = 2.f * frcp(1.f + fexp2(-2.88539008177792681f * xg_)) - 1.f;   \
        const float cn_ = sigm(xf_) * CARR[R] + sigm(xi_) * tg_;                        \
        CARR[R] = cn_;                                                                  \
        const float so_ = sigm(xo_);                                                    \
        const float rr_ = frcp(1.f + fexp2(-2.88539008177792681f * cn_));               \
        (PTR)[(HWB) + (R) * 8] = f2bfbits(__builtin_fmaf(2.f * so_, rr_, -so_));        \
    }

// ---------------------------------------------------------------------------
// Fused 2-layer LSTM with layer-specialized wave groups.
//   Waves {0,2,5,7} (group 0) run layer 1; waves {1,3,4,6} (group 1) run
//   layer 2 one step behind, consuming h1 from LDS. Each SIMD hosts one wave
//   of each group (under either i%4 or i/2 wave->SIMD mapping) -> the two
//   co-resident waves run DIFFERENT programs, so gate VALU of one overlaps
//   MFMA of the other (m114 dual-issue). hs0 HBM roundtrip eliminated.
//   wl = wave>>1 gives each group a bijection onto col-blocks 0..3
//   (cols [32*wl, 32*wl+32) per wave, 2 sub-tiles of 16).
//   91 intervals; A active k=0..89 (h1(k)), B active k=1..90 (h2(k-1)).
//   One barrier per interval; per-group barrier counts match exactly.
// ---------------------------------------------------------------------------
__global__ __launch_bounds__(512, 2) void lstm_fused(
    const float* __restrict__ x, const float2* __restrict__ stats,
    const u16* __restrict__ Uhat,
    const float* __restrict__ Whh0, const float* __restrict__ bih0,
    const float* __restrict__ bhh0,
    const float* __restrict__ Wih1, const float* __restrict__ Whh1,
    const float* __restrict__ bih1, const float* __restrict__ bhh1,
    u16* __restrict__ hlast) {
    // [par][mt][kchunk][row][8]
    __shared__ __align__(16) u16 s_z[2][2][4][16][8];     // 4 KB (z aug, K=32)
    __shared__ __align__(16) u16 s_h1[2][2][16][16][8];   // 16 KB
    __shared__ __align__(16) u16 s_h2[2][2][16][16][8];   // 16 KB

    const int tid = threadIdx.x;
    const int wave = tid >> 6, lane = tid & 63, quad = lane >> 4, n16 = lane & 15;
    const int b0 = blockIdx.x * 32;
    const int group = (wave ^ (wave >> 2)) & 1;  // 0 = layer-1, 1 = layer-2
    const int wl = wave >> 1;                    // col-block within group, 0..3

    for (int i = tid; i < 2 * 2 * 4 * 16 * 8; i += 512) ((u16*)s_z)[i] = 0;
    for (int i = tid; i < 2 * 16 * 16 * 8; i += 512) {
        ((u16*)s_h1[1])[i] = 0;   // h1(-1) = 0
        ((u16*)s_h2[0])[i] = 0;   // h2(-1) = 0
    }

    const f32x4 zero4 = {0.f, 0.f, 0.f, 0.f};
    // h write base for sub-tile ct: col = wl*32 + ct*16 + n16
    const int hwb0 = ((wl * 4 + 0 + (n16 >> 3)) * 16 + quad * 4) * 8 + (n16 & 7);
    const int hwb1 = ((wl * 4 + 2 + (n16 >> 3)) * 16 + quad * 4) * 8 + (n16 & 7);

    __syncthreads();  // BAR0: zero-init visible

    if (group == 0) {
        // ================= layer-1 wave group =================
        bf16x8 bU[4][2], bW0[4][2][4];
        float bias[4][2];
#pragma unroll
        for (int g = 0; g < 4; ++g)
#pragma unroll
            for (int ct = 0; ct < 2; ++ct) {
                const int wrow = g * 128 + wl * 32 + ct * 16 + n16;
                bias[g][ct] = bih0[wrow] + bhh0[wrow];
                bU[g][ct] = *(const bf16x8*)&Uhat[wrow * 32 + quad * 8];
#pragma unroll
                for (int kk = 0; kk < 4; ++kk) {
                    const float* ph = Whh0 + (long)wrow * 128 + kk * 32 + quad * 8;
                    bf16x8 bh;
#pragma unroll
                    for (int j = 0; j < 8; ++j) bh[j] = (__bf16)ph[j];
                    bW0[g][ct][kk] = bh;
                }
            }

        float c1[2][2][4];
#pragma unroll
        for (int mt = 0; mt < 2; ++mt)
#pragma unroll
            for (int ct = 0; ct < 2; ++ct)
#pragma unroll
                for (int r = 0; r < 4; ++r) c1[mt][ct][r] = 0.f;

        // staging: 8 lanes x 4 A-waves = 32 units, one row each, both chunks
        const bool stager = (lane < 8);
        const int srow = wl * 8 + lane, smt = srow >> 4, sm = srow & 15;
        const long srowg = (long)(b0 + srow) * T;

        if (stager) {  // stage z(0) -> parity 0
            const float2 st0 = stats[srowg];
            const float* xp = x + srowg * 7;
            const float rs = st0.x;
            uint4 v0 = {pk2(rs * xp[0], rs * xp[1]), pk2(rs * xp[2], rs * xp[3]),
                        pk2(rs * xp[4], rs * xp[5]), pk2(rs * xp[6], rs)};
            uint4 v1 = {pk2(st0.y, 1.f), 0u, 0u, 0u};
            *(uint4*)&s_z[0][smt][0][sm][0] = v0;
            *(uint4*)&s_z[0][smt][1][sm][0] = v1;
        }
        __syncthreads();  // BAR_P

#pragma unroll 1
        for (int k = 0; k < 90; ++k) {
            const int par = k & 1;
            float2 nst = {};
            float nx0 = 0, nx1 = 0, nx2 = 0, nx3 = 0, nx4 = 0, nx5 = 0, nx6 = 0;
            const bool pre = stager && (k < 89);
            if (pre) {
                nst = stats[srowg + k + 1];
                const float* xp = x + (srowg + k + 1) * 7;
                nx0 = xp[0]; nx1 = xp[1]; nx2 = xp[2]; nx3 = xp[3];
                nx4 = xp[4]; nx5 = xp[5]; nx6 = xp[6];
            }
#pragma unroll
            for (int mt = 0; mt < 2; ++mt) {
                const bf16x8 az = *(const bf16x8*)&s_z[par][mt][quad][n16][0];
                bf16x8 ah[4];
#pragma unroll
                for (int kk = 0; kk < 4; ++kk)
                    ah[kk] = *(const bf16x8*)&s_h1[par ^ 1][mt][kk * 4 + quad][n16][0];
                f32x4 acc[2][4];
#pragma unroll
                for (int ct = 0; ct < 2; ++ct)
#pragma unroll
                    for (int g = 0; g < 4; ++g) {
                        f32x4 a = __builtin_amdgcn_mfma_f32_16x16x32_bf16(az, bU[g][ct], zero4, 0, 0, 0);
#pragma unroll
                        for (int kk = 0; kk < 4; ++kk)
                            a = __builtin_amdgcn_mfma_f32_16x16x32_bf16(ah[kk], bW0[g][ct][kk], a, 0, 0, 0);
                        acc[ct][g] = a;
                    }
                u16* hp = &s_h1[par][mt][0][0][0];
#pragma unroll
                for (int r = 0; r < 4; ++r)
                    GATE_E(acc[0], c1[mt][0], hp, hwb0, r, bias[0][0], bias[1][0], bias[2][0], bias[3][0])
#pragma unroll
                for (int r = 0; r < 4; ++r)
                    GATE_E(acc[1], c1[mt][1], hp, hwb1, r, bias[0][1], bias[1][1], bias[2][1], bias[3][1])
            }
            if (pre) {  // commit z(k+1) -> parity par^1
                const float rs = nst.x;
                uint4 v0 = {pk2(rs * nx0, rs * nx1), pk2(rs * nx2, rs * nx3),
                            pk2(rs * nx4, rs * nx5), pk2(rs * nx6, rs)};
                uint4 v1 = {pk2(nst.y, 1.f), 0u, 0u, 0u};
                *(uint4*)&s_z[par ^ 1][smt][0][sm][0] = v0;
                *(uint4*)&s_z[par ^ 1][smt][1][sm][0] = v1;
            }
            __syncthreads();  // end of interval k
        }
        __syncthreads();  // interval 90 (B's last step)
    } else {
        // ================= layer-2 wave group =================
        bf16x8 bWi[4][2][4], bWh[4][2][4];
        float bias[4][2];
#pragma unroll
        for (int g = 0; g < 4; ++g)
#pragma unroll
            for (int ct = 0; ct < 2; ++ct) {
                const int wrow = g * 128 + wl * 32 + ct * 16 + n16;
                bias[g][ct] = bih1[wrow] + bhh1[wrow];
#pragma unroll
                for (int kk = 0; kk < 4; ++kk) {
                    const float* pi = Wih1 + (long)wrow * 128 + kk * 32 + quad * 8;
                    const float* ph = Whh1 + (long)wrow * 128 + kk * 32 + quad * 8;
                    bf16x8 bi, bh;
#pragma unroll
                    for (int j = 0; j < 8; ++j) { bi[j] = (__bf16)pi[j]; bh[j] = (__bf16)ph[j]; }
                    bWi[g][ct][kk] = bi; bWh[g][ct][kk] = bh;
                }
            }

        float c2[2][2][4];
#pragma unroll
        for (int mt = 0; mt < 2; ++mt)
#pragma unroll
            for (int ct = 0; ct < 2; ++ct)
#pragma unroll
                for (int r = 0; r < 4; ++r) c2[mt][ct][r] = 0.f;

        __syncthreads();  // BAR_P
        __syncthreads();  // interval 0 (B idle; A computes h1(0))

#pragma unroll 1
        for (int k = 1; k <= 90; ++k) {
            const int par = k & 1;
#pragma unroll
            for (int mt = 0; mt < 2; ++mt) {
                bf16x8 a1[4], a2[4];
#pragma unroll
                for (int kk = 0; kk < 4; ++kk) {
                    a1[kk] = *(const bf16x8*)&s_h1[par ^ 1][mt][kk * 4 + quad][n16][0];
                    a2[kk] = *(const bf16x8*)&s_h2[par ^ 1][mt][kk * 4 + quad][n16][0];
                }
                f32x4 acc[2][4];
#pragma unroll
                for (int ct = 0; ct < 2; ++ct)
#pragma unroll
                    for (int g = 0; g < 4; ++g) {
                        f32x4 a = __builtin_amdgcn_mfma_f32_16x16x32_bf16(a1[0], bWi[g][ct][0], zero4, 0, 0, 0);
                        a = __builtin_amdgcn_mfma_f32_16x16x32_bf16(a2[0], bWh[g][ct][0], a, 0, 0, 0);
#pragma unroll
                        for (int kk = 1; kk < 4; ++kk) {
                            a = __builtin_amdgcn_mfma_f32_16x16x32_bf16(a1[kk], bWi[g][ct][kk], a, 0, 0, 0);
                            a = __builtin_amdgcn_mfma_f32_16x16x32_bf16(a2[kk], bWh[g][ct][kk], a, 0, 0, 0);
                        }
                        acc[ct][g] = a;
                    }
                u16* hp = &s_h2[par][mt][0][0][0];
#pragma unroll
                for (int r = 0; r < 4; ++r)
                    GATE_E(acc[0], c2[mt][0], hp, hwb0, r, bias[0][0], bias[1][0], bias[2][0], bias[3][0])
#pragma unroll
                for (int r = 0; r < 4; ++r)
                    GATE_E(acc[1], c2[mt][1], hp, hwb1, r, bias[0][1], bias[1][1], bias[2][1], bias[3][1])
            }
            __syncthreads();  // end of interval k
        }
    }

    {  // epilogue (converged): h2(89) lives at parity 0 (interval 90)
        const int ftile = tid >> 8, fin = tid & 255;
        const int fm = fin & 15, fk = fin >> 4;
        const uint4 hv = *(const uint4*)&s_h2[0][ftile][fk][fm][0];
        *(uint4*)(hlast + (size_t)(b0 + ftile * 16 + fm) * 128 + fk * 8) = hv;
    }
}

// ---------------------------------------------------------------------------
// Head: 4 rows per wave, 16 rows per block, grid 512. (unchanged)
// ---------------------------------------------------------------------------
__global__ __launch_bounds__(256) void dense_head(
    const u16* __restrict__ hlast, const float* __restrict__ g_ln,
    const float* __restrict__ be_ln, const float* __restrict__ W_d1,
    const float* __restrict__ b_d1, const float* __restrict__ W_d2,
    const float* __restrict__ b_d2, const float* __restrict__ W_d3,
    const float* __restrict__ b_d3, float* __restrict__ out) {
    __shared__ float s_ln[16][128];
    __shared__ float s_d1[16][128];
    __shared__ float s_d2[16][64];
    const int wave = threadIdx.x >> 6, lane = threadIdx.x & 63;
    const long base = (long)blockIdx.x * 16;
    const int R = wave * 4;

#pragma unroll
    for (int rr = 0; rr < 4; ++rr) {
        const long row = base + R + rr;
        const u32 packed = ((const u32*)hlast)[row * 64 + lane];
        float v0 = bfbits2f(packed & 0xffffu), v1 = bfbits2f(packed >> 16);
        const float s = wave_sum(v0 + v1);
        const float q = wave_sum(v0 * v0 + v1 * v1);
        const float mu = s * (1.f / 128.f);
        const float rstd = frsq(q * (1.f / 128.f) - mu * mu + 1e-5f);
        const int h0 = 2 * lane;
        s_ln[R + rr][h0] = (v0 - mu) * rstd * g_ln[h0] + be_ln[h0];
        s_ln[R + rr][h0 + 1] = (v1 - mu) * rstd * g_ln[h0 + 1] + be_ln[h0 + 1];
    }
    __syncthreads();

#pragma unroll
    for (int half = 0; half < 2; ++half) {
        const int o = lane + 64 * half;
        float a[4] = {b_d1[o], b_d1[o], b_d1[o], b_d1[o]};
        const float4* wr = (const float4*)(W_d1 + (long)o * 128);
#pragma unroll 8
        for (int k = 0; k < 32; ++k) {
            const float4 wv = wr[k];
#pragma unroll
            for (int rr = 0; rr < 4; ++rr) {
                const float4 xv = ((const float4*)s_ln[R + rr])[k];
                a[rr] += wv.x * xv.x + wv.y * xv.y + wv.z * xv.z + wv.w * xv.w;
            }
        }
#pragma unroll
        for (int rr = 0; rr < 4; ++rr) s_d1[R + rr][o] = fmaxf(a[rr], 0.f);
    }
    __syncthreads();

    {
        float a[4] = {b_d2[lane], b_d2[lane], b_d2[lane], b_d2[lane]};
        const float4* wr = (const float4*)(W_d2 + (long)lane * 128);
#pragma unroll 8
        for (int k = 0; k < 32; ++k) {
            const float4 wv = wr[k];
#pragma unroll
            for (int rr = 0; rr < 4; ++rr) {
                const float4 xv = ((const float4*)s_d1[R + rr])[k];
                a[rr] += wv.x * xv.x + wv.y * xv.y + wv.z * xv.z + wv.w * xv.w;
            }
        }
#pragma unroll
        for (int rr = 0; rr < 4; ++rr) s_d2[R + rr][lane] = fmaxf(a[rr], 0.f);
    }
    __syncthreads();

    if (lane < NOUT) {
        float a[4] = {b_d3[lane], b_d3[lane], b_d3[lane], b_d3[lane]};
        const float4* wr = (const float4*)(W_d3 + (long)lane * 64);
#pragma unroll
        for (int k = 0; k < 16; ++k) {
            const float4 wv = wr[k];
#pragma unroll
            for (int rr = 0; rr < 4; ++rr) {
                const float4 xv = ((const float4*)s_d2[R + rr])[k];
                a[rr] += wv.x * xv.x + wv.y * xv.y + wv.z * xv.z + wv.w * xv.w;
            }
        }
#pragma unroll
        for (int rr = 0; rr < 4; ++rr) out[(base + R + rr) * NOUT + lane] = a[rr];
    }
}

// ---------------------------------------------------------------------------
extern "C" void kernel_launch(void* const* d_in, const int* in_sizes, int n_in,
                              void* d_out, int out_size, void* d_ws, size_t ws_size,
                              hipStream_t stream) {
    const float* x = (const float*)d_in[0];
    const float* W_in = (const float*)d_in[1];
    const float* b_in = (const float*)d_in[2];
    const float* g_in = (const float*)d_in[3];
    const float* be_in = (const float*)d_in[4];
    const float* Wih0 = (const float*)d_in[5];
    const float* Whh0 = (const float*)d_in[6];
    const float* bih0 = (const float*)d_in[7];
    const float* bhh0 = (const float*)d_in[8];
    const float* Wih1 = (const float*)d_in[9];
    const float* Whh1 = (const float*)d_in[10];
    const float* bih1 = (const float*)d_in[11];
    const float* bhh1 = (const float*)d_in[12];
    const float* g_ln = (const float*)d_in[13];
    const float* be_ln = (const float*)d_in[14];
    const float* W_d1 = (const float*)d_in[15];
    const float* b_d1 = (const float*)d_in[16];
    const float* W_d2 = (const float*)d_in[17];
    const float* b_d2 = (const float*)d_in[18];
    const float* W_d3 = (const float*)d_in[19];
    const float* b_d3 = (const float*)d_in[20];
    float* out = (float*)d_out;

    // workspace layout: aux | Uhat | stats | hlast  (hs0 eliminated by fusion)
    char* w = (char*)d_ws;
    float* aux = (float*)w;               w += 512;
    u16* Uhat = (u16*)w;                  w += 512 * 32 * sizeof(u16);
    float2* stats = (float2*)w;           w += (size_t)B * T * sizeof(float2);
    u16* hlast = (u16*)w;

    prep_aux<<<1, 512, 0, stream>>>(W_in, b_in, g_in, be_in, Wih0, aux, Uhat);
    prep_stats<<<(B * T) / 256, 256, 0, stream>>>(x, aux, stats);
    lstm_fused<<<B / 32, 512, 0, stream>>>(x, stats, Uhat, Whh0, bih0, bhh0,
                                           Wih1, Whh1, bih1, bhh1, hlast);
    dense_head<<<B / 16, 256, 0, stream>>>(hlast, g_ln, be_ln, W_d1, b_d1, W_d2, b_d2,
                                           W_d3, b_d3, out);
}

// Round 7
// 644.731 us; speedup vs baseline: 2.3251x; 2.3251x over previous
//
#include <hip/hip_runtime.h>

#define DEV __device__ __forceinline__
typedef unsigned short u16;
typedef unsigned int u32;
typedef __bf16 bf16x8 __attribute__((ext_vector_type(8)));
typedef float f32x4 __attribute__((ext_vector_type(4)));

static constexpr int B = 8192, T = 90, F = 7, H = 128, NOUT = 30;

DEV float fexp2(float x) { return __builtin_amdgcn_exp2f(x); }
DEV float frcp(float x) { return __builtin_amdgcn_rcpf(x); }
DEV float frsq(float x) { return __builtin_amdgcn_rsqf(x); }
DEV float sigm(float x) { return frcp(1.f + fexp2(-1.44269504088896341f * x)); }
DEV u16 f2bfbits(float f) { __bf16 b = (__bf16)f; return __builtin_bit_cast(u16, b); }
DEV float bfbits2f(u32 u) { return __builtin_bit_cast(float, u << 16); }
DEV u32 pk2(float a, float b) { return (u32)f2bfbits(a) | ((u32)f2bfbits(b) << 16); }

DEV float wave_sum(float v) {
#pragma unroll
    for (int m = 32; m; m >>= 1) v += __shfl_xor(v, m, 64);
    return v;
}

// ---------------------------------------------------------------------------
// prep_aux: one 512-thread block. (unchanged)
// ---------------------------------------------------------------------------
__global__ __launch_bounds__(512) void prep_aux(
    const float* __restrict__ W_in, const float* __restrict__ b_in,
    const float* __restrict__ g_in, const float* __restrict__ be_in,
    const float* __restrict__ Wih0, float* __restrict__ aux, u16* __restrict__ Uhat) {
    const int tid = threadIdx.x;
    if (tid < 7) {
        float sm = 0.f, sp = 0.f;
        for (int h = 0; h < 128; ++h) { const float w = W_in[h * 7 + tid]; sm += w; sp += w * b_in[h]; }
        aux[tid] = sm * (1.f / 128.f); aux[64 + tid] = sp * (1.f / 128.f);
    } else if (tid < 56) {
        const int cd = tid - 7, cc = cd / 7, dd = cd % 7;
        float s = 0.f;
        for (int h = 0; h < 128; ++h) s += W_in[h * 7 + cc] * W_in[h * 7 + dd];
        aux[8 + cd] = s * (1.f / 128.f);
    } else if (tid == 56) {
        float s = 0.f; for (int h = 0; h < 128; ++h) s += b_in[h];
        aux[7] = s * (1.f / 128.f);
    } else if (tid == 57) {
        float s = 0.f; for (int h = 0; h < 128; ++h) s += b_in[h] * b_in[h];
        aux[72] = s * (1.f / 128.f);
    }
    float acc[10];
#pragma unroll
    for (int i = 0; i < 10; ++i) acc[i] = 0.f;
    const float* wr = Wih0 + (long)tid * 128;
    for (int h = 0; h < 128; ++h) {
        const float wv = wr[h], wg = wv * g_in[h];
#pragma unroll
        for (int cc = 0; cc < 7; ++cc) acc[cc] += wg * W_in[h * 7 + cc];
        acc[7] += wg * b_in[h]; acc[8] += wg; acc[9] += wv * be_in[h];
    }
    u16* dst = Uhat + tid * 32;
#pragma unroll
    for (int cc = 0; cc < 10; ++cc) dst[cc] = f2bfbits(acc[cc]);
#pragma unroll
    for (int cc = 10; cc < 32; ++cc) dst[cc] = 0;
}

// ---------------------------------------------------------------------------
// prep_stats (unchanged)
// ---------------------------------------------------------------------------
__global__ __launch_bounds__(256) void prep_stats(
    const float* __restrict__ x, const float* __restrict__ aux,
    float2* __restrict__ stats) {
    __shared__ float sa[80];
    const int tid = threadIdx.x;
    if (tid < 80) sa[tid] = aux[tid];
    __syncthreads();
    const long idx = (long)blockIdx.x * 256 + tid;
    const float* xr = x + idx * 7;
    float xv[7];
#pragma unroll
    for (int cc = 0; cc < 7; ++cc) xv[cc] = xr[cc];
    float mu = sa[7];
#pragma unroll
    for (int cc = 0; cc < 7; ++cc) mu += sa[cc] * xv[cc];
    float q = sa[72];
#pragma unroll
    for (int cc = 0; cc < 7; ++cc) {
        float tacc = 2.f * sa[64 + cc];
#pragma unroll
        for (int dd = 0; dd < 7; ++dd) tacc += sa[8 + cc * 7 + dd] * xv[dd];
        q += xv[cc] * tacc;
    }
    const float rstd = frsq(q - mu * mu + 1e-5f);
    stats[idx] = make_float2(rstd, -rstd * mu);
}

// ---------------------------------------------------------------------------
// Gate math for one accumulator row r. Writes h as bf16 into SHROW.
// References outer-scope: bias[], hwbase.
// ---------------------------------------------------------------------------
#define GATE_R(ACC, CARR, SHROW, R)                                                     \
    {                                                                                   \
        const float xi_ = ACC[0][R] + bias[0];                                          \
        const float xf_ = ACC[1][R] + bias[1];                                          \
        const float xg_ = ACC[2][R] + bias[2];                                          \
        const float xo_ = ACC[3][R] + bias[3];                                          \
        const float tg_ = 2.f * frcp(1.f + fexp2(-2.88539008177792681f * xg_)) - 1.f;   \
        const float cn_ = sigm(xf_) * CARR[R] + sigm(xi_) * tg_;                        \
        CARR[R] = cn_;                                                                  \
        const float so_ = sigm(xo_);                                                    \
        const float rr_ = frcp(1.f + fexp2(-2.88539008177792681f * cn_));               \
        SHROW[hwbase + (R) * 8] = f2bfbits(__builtin_fmaf(2.f * so_, rr_, -so_));       \
    }

// ---------------------------------------------------------------------------
// Layer-1 LSTM, R6: 16 batch rows / block (mt tile removed), grid 512 ->
// TWO blocks per CU. Independent barrier domains drift freely, so each SIMD
// carries one MFMA-phase wave and one VALU-phase wave on average (m114
// dual-issue) without any scheduling tricks. Weight residency per wave is
// unchanged (16 cols -> fits the 128-reg cap that (512,2) enforces).
// ---------------------------------------------------------------------------
__global__ __launch_bounds__(512, 2) void lstm_rec_l1(
    const float* __restrict__ x, const float2* __restrict__ stats,
    const u16* __restrict__ Uhat, const float* __restrict__ Whh,
    const float* __restrict__ bih, const float* __restrict__ bhh,
    u16* __restrict__ hs) {
    __shared__ __align__(16) u16 s_z[2][4][16][8];   // [par][kk8][row][8] 2 KB
    __shared__ __align__(16) u16 s_h[2][16 * 128];   // [par] 8 KB

    const int tid = threadIdx.x;
    const int wave = tid >> 6, lane = tid & 63, quad = lane >> 4, n16 = lane & 15;
    const int b0 = blockIdx.x * 16;

    for (int i = tid; i < 2 * 4 * 16 * 8; i += 512) ((u16*)s_z)[i] = 0;
    for (int i = tid; i < 16 * 128; i += 512) s_h[1][i] = 0;

    bf16x8 bU[4], bWhh[4][4];
    float bias[4];
#pragma unroll
    for (int g = 0; g < 4; ++g) {
        const int wrow = g * 128 + 16 * wave + n16;
        bias[g] = bih[wrow] + bhh[wrow];
        bU[g] = *(const bf16x8*)&Uhat[wrow * 32 + quad * 8];
#pragma unroll
        for (int kk = 0; kk < 4; ++kk) {
            const float* ph = Whh + (long)wrow * 128 + kk * 32 + quad * 8;
            bf16x8 bh;
#pragma unroll
            for (int j = 0; j < 8; ++j) bh[j] = (__bf16)ph[j];
            bWhh[g][kk] = bh;
        }
    }

    const f32x4 zero4 = {0.f, 0.f, 0.f, 0.f};
    float c[4];
#pragma unroll
    for (int r = 0; r < 4; ++r) c[r] = 0.f;

    // staging: 4 lanes/wave, 32 units cover 16 rows x 2 kk8-chunks
    const bool stager = (lane < 4);
    const int tau = wave * 4 + lane;
    const int srow = tau & 15, skk8 = tau >> 4;
    const long srowg = (long)(b0 + srow) * T;

    // flush map (tid<256): 16 rows x 16 col-chunks
    const int fm = tid & 15, fkk8 = (tid >> 4) & 15;
    const int fldsoff = (fkk8 * 16 + fm) * 8;
    const size_t fgrow = (size_t)(b0 + fm) * T;
    const int fgcol = fkk8 * 8;

    const int hwbase = (2 * wave + (n16 >> 3)) * 128 + quad * 32 + (n16 & 7);

    __syncthreads();  // zero-init visible before prologue staging stores

    if (stager) {  // stage z(0) -> parity 0
        const float2 st0 = stats[srowg];
        u32 p0, p1, p2, p3;
        if (skk8 == 0) {
            const float* xp = x + srowg * 7;
            const float rs = st0.x;
            p0 = pk2(rs * xp[0], rs * xp[1]); p1 = pk2(rs * xp[2], rs * xp[3]);
            p2 = pk2(rs * xp[4], rs * xp[5]); p3 = pk2(rs * xp[6], rs);
        } else { p0 = pk2(st0.y, 1.f); p1 = 0; p2 = 0; p3 = 0; }
        *(uint4*)&s_z[0][skk8][srow][0] = (uint4){p0, p1, p2, p3};
    }
    __syncthreads();

#pragma unroll 1
    for (int t = 0; t < T; ++t) {
        const int par = t & 1;
        const bool hasPre = stager && (t + 1 < T);
        float2 nst = {};
        float nx[7];
        if (hasPre) {
            nst = stats[srowg + t + 1];
            if (skk8 == 0) {
                const float* xp = x + (srowg + t + 1) * 7;
#pragma unroll
                for (int j = 0; j < 7; ++j) nx[j] = xp[j];
            }
        }
        if (t > 0 && tid < 256) {  // flush h(t-1) from the read-side buffer
            const uint4 hv = *(const uint4*)&s_h[par ^ 1][fldsoff];
            *(uint4*)(hs + (fgrow + (t - 1)) * 128 + fgcol) = hv;
        }

        const bf16x8 az = *(const bf16x8*)&s_z[par][quad][n16][0];
        bf16x8 ah[4];
#pragma unroll
        for (int kk = 0; kk < 4; ++kk)
            ah[kk] = *(const bf16x8*)&s_h[par ^ 1][((kk * 4 + quad) * 16 + n16) * 8];
        f32x4 acc[4];
#pragma unroll
        for (int g = 0; g < 4; ++g) {
            f32x4 a = __builtin_amdgcn_mfma_f32_16x16x32_bf16(az, bU[g], zero4, 0, 0, 0);
#pragma unroll
            for (int kk = 0; kk < 4; ++kk)
                a = __builtin_amdgcn_mfma_f32_16x16x32_bf16(ah[kk], bWhh[g][kk], a, 0, 0, 0);
            acc[g] = a;
        }
        {
            u16* hp = s_h[par];
            GATE_R(acc, c, hp, 0)
            GATE_R(acc, c, hp, 1)
            GATE_R(acc, c, hp, 2)
            GATE_R(acc, c, hp, 3)
        }

        if (hasPre) {  // commit z(t+1)
            u32 p0, p1, p2, p3;
            if (skk8 == 0) {
                const float rs = nst.x;
                p0 = pk2(rs * nx[0], rs * nx[1]); p1 = pk2(rs * nx[2], rs * nx[3]);
                p2 = pk2(rs * nx[4], rs * nx[5]); p3 = pk2(rs * nx[6], rs);
            } else { p0 = pk2(nst.y, 1.f); p1 = 0; p2 = 0; p3 = 0; }
            *(uint4*)&s_z[par ^ 1][skk8][srow][0] = (uint4){p0, p1, p2, p3};
        }
        __syncthreads();
    }
    if (tid < 256) {  // epilogue: h(T-1) at parity 1
        const uint4 hv = *(const uint4*)&s_h[1][fldsoff];
        *(uint4*)(hs + (fgrow + (T - 1)) * 128 + fgcol) = hv;
    }
}

// ---------------------------------------------------------------------------
// Layer-2 LSTM, R6: 16 rows / block, grid 512 (2 blocks/CU). Same step
// structure as R1; writes only hlast.
// ---------------------------------------------------------------------------
__global__ __launch_bounds__(512, 2) void lstm_rec_l2(
    const float* __restrict__ Wih, const float* __restrict__ Whh,
    const float* __restrict__ bih, const float* __restrict__ bhh,
    const u16* __restrict__ xin, u16* __restrict__ hlast) {
    __shared__ __align__(16) u16 s_x[2][16 * 128];   // 8 KB
    __shared__ __align__(16) u16 s_h[2][16 * 128];   // 8 KB

    const int tid = threadIdx.x;
    const int wave = tid >> 6, lane = tid & 63, quad = lane >> 4, n16 = lane & 15;
    const int b0 = blockIdx.x * 16;

    for (int i = tid; i < 16 * 128; i += 512) s_h[1][i] = 0;

    bf16x8 bWih[4][4], bWhh[4][4];
    float bias[4];
#pragma unroll
    for (int g = 0; g < 4; ++g) {
        const int wrow = g * 128 + 16 * wave + n16;
        bias[g] = bih[wrow] + bhh[wrow];
#pragma unroll
        for (int kk = 0; kk < 4; ++kk) {
            const float* pi = Wih + (long)wrow * 128 + kk * 32 + quad * 8;
            const float* ph = Whh + (long)wrow * 128 + kk * 32 + quad * 8;
            bf16x8 bi, bh;
#pragma unroll
            for (int j = 0; j < 8; ++j) { bi[j] = (__bf16)pi[j]; bh[j] = (__bf16)ph[j]; }
            bWih[g][kk] = bi; bWhh[g][kk] = bh;
        }
    }

    const f32x4 zero4 = {0.f, 0.f, 0.f, 0.f};
    float c[4];
#pragma unroll
    for (int r = 0; r < 4; ++r) c[r] = 0.f;

    // staging/flush map (tid<256): 16 rows x 16 col-chunks
    const int ssm = tid & 15, sskk8 = (tid >> 4) & 15;
    const u16* gsrc = xin + (size_t)(b0 + ssm) * T * 128 + sskk8 * 8;
    const int soff = (sskk8 * 16 + ssm) * 8;

    const int hwbase = (2 * wave + (n16 >> 3)) * 128 + quad * 32 + (n16 & 7);

    if (tid < 256) {  // prologue stage x(0) -> parity 0
        const uint4 v = *(const uint4*)gsrc;
        *(uint4*)&s_x[0][soff] = v;
    }
    __syncthreads();

#pragma unroll 1
    for (int t = 0; t < T; ++t) {
        const int par = t & 1;
        uint4 pre = {};
        const bool hasPre = (t + 1 < T) && (tid < 256);
        if (hasPre) pre = *(const uint4*)(gsrc + (size_t)(t + 1) * 128);

        bf16x8 aln[4], ah[4];
#pragma unroll
        for (int kk = 0; kk < 4; ++kk) {
            const int ro = ((kk * 4 + quad) * 16 + n16) * 8;
            aln[kk] = *(const bf16x8*)&s_x[par][ro];
            ah[kk] = *(const bf16x8*)&s_h[par ^ 1][ro];
        }
        f32x4 acc[4];
#pragma unroll
        for (int g = 0; g < 4; ++g) {
            f32x4 a = __builtin_amdgcn_mfma_f32_16x16x32_bf16(aln[0], bWih[g][0], zero4, 0, 0, 0);
            a = __builtin_amdgcn_mfma_f32_16x16x32_bf16(ah[0], bWhh[g][0], a, 0, 0, 0);
#pragma unroll
            for (int kk = 1; kk < 4; ++kk) {
                a = __builtin_amdgcn_mfma_f32_16x16x32_bf16(aln[kk], bWih[g][kk], a, 0, 0, 0);
                a = __builtin_amdgcn_mfma_f32_16x16x32_bf16(ah[kk], bWhh[g][kk], a, 0, 0, 0);
            }
            acc[g] = a;
        }
        {
            u16* hp = s_h[par];
            GATE_R(acc, c, hp, 0)
            GATE_R(acc, c, hp, 1)
            GATE_R(acc, c, hp, 2)
            GATE_R(acc, c, hp, 3)
        }
        if (hasPre) *(uint4*)&s_x[par ^ 1][soff] = pre;
        __syncthreads();
    }
    if (tid < 256) {  // h(T-1) written at parity 1
        const uint4 hv = *(const uint4*)&s_h[1][soff];
        *(uint4*)(hlast + (size_t)(b0 + ssm) * 128 + sskk8 * 8) = hv;
    }
}

// ---------------------------------------------------------------------------
// Head: 4 rows per wave, 16 rows per block, grid 512. (unchanged)
// ---------------------------------------------------------------------------
__global__ __launch_bounds__(256) void dense_head(
    const u16* __restrict__ hlast, const float* __restrict__ g_ln,
    const float* __restrict__ be_ln, const float* __restrict__ W_d1,
    const float* __restrict__ b_d1, const float* __restrict__ W_d2,
    const float* __restrict__ b_d2, const float* __restrict__ W_d3,
    const float* __restrict__ b_d3, float* __restrict__ out) {
    __shared__ float s_ln[16][128];
    __shared__ float s_d1[16][128];
    __shared__ float s_d2[16][64];
    const int wave = threadIdx.x >> 6, lane = threadIdx.x & 63;
    const long base = (long)blockIdx.x * 16;
    const int R = wave * 4;

#pragma unroll
    for (int rr = 0; rr < 4; ++rr) {
        const long row = base + R + rr;
        const u32 packed = ((const u32*)hlast)[row * 64 + lane];
        float v0 = bfbits2f(packed & 0xffffu), v1 = bfbits2f(packed >> 16);
        const float s = wave_sum(v0 + v1);
        const float q = wave_sum(v0 * v0 + v1 * v1);
        const float mu = s * (1.f / 128.f);
        const float rstd = frsq(q * (1.f / 128.f) - mu * mu + 1e-5f);
        const int h0 = 2 * lane;
        s_ln[R + rr][h0] = (v0 - mu) * rstd * g_ln[h0] + be_ln[h0];
        s_ln[R + rr][h0 + 1] = (v1 - mu) * rstd * g_ln[h0 + 1] + be_ln[h0 + 1];
    }
    __syncthreads();

#pragma unroll
    for (int half = 0; half < 2; ++half) {
        const int o = lane + 64 * half;
        float a[4] = {b_d1[o], b_d1[o], b_d1[o], b_d1[o]};
        const float4* wr = (const float4*)(W_d1 + (long)o * 128);
#pragma unroll 8
        for (int k = 0; k < 32; ++k) {
            const float4 wv = wr[k];
#pragma unroll
            for (int rr = 0; rr < 4; ++rr) {
                const float4 xv = ((const float4*)s_ln[R + rr])[k];
                a[rr] += wv.x * xv.x + wv.y * xv.y + wv.z * xv.z + wv.w * xv.w;
            }
        }
#pragma unroll
        for (int rr = 0; rr < 4; ++rr) s_d1[R + rr][o] = fmaxf(a[rr], 0.f);
    }
    __syncthreads();

    {
        float a[4] = {b_d2[lane], b_d2[lane], b_d2[lane], b_d2[lane]};
        const float4* wr = (const float4*)(W_d2 + (long)lane * 128);
#pragma unroll 8
        for (int k = 0; k < 32; ++k) {
            const float4 wv = wr[k];
#pragma unroll
            for (int rr = 0; rr < 4; ++rr) {
                const float4 xv = ((const float4*)s_d1[R + rr])[k];
                a[rr] += wv.x * xv.x + wv.y * xv.y + wv.z * xv.z + wv.w * xv.w;
            }
        }
#pragma unroll
        for (int rr = 0; rr < 4; ++rr) s_d2[R + rr][lane] = fmaxf(a[rr], 0.f);
    }
    __syncthreads();

    if (lane < NOUT) {
        float a[4] = {b_d3[lane], b_d3[lane], b_d3[lane], b_d3[lane]};
        const float4* wr = (const float4*)(W_d3 + (long)lane * 64);
#pragma unroll
        for (int k = 0; k < 16; ++k) {
            const float4 wv = wr[k];
#pragma unroll
            for (int rr = 0; rr < 4; ++rr) {
                const float4 xv = ((const float4*)s_d2[R + rr])[k];
                a[rr] += wv.x * xv.x + wv.y * xv.y + wv.z * xv.z + wv.w * xv.w;
            }
        }
#pragma unroll
        for (int rr = 0; rr < 4; ++rr) out[(base + R + rr) * NOUT + lane] = a[rr];
    }
}

// ---------------------------------------------------------------------------
extern "C" void kernel_launch(void* const* d_in, const int* in_sizes, int n_in,
                              void* d_out, int out_size, void* d_ws, size_t ws_size,
                              hipStream_t stream) {
    const float* x = (const float*)d_in[0];
    const float* W_in = (const float*)d_in[1];
    const float* b_in = (const float*)d_in[2];
    const float* g_in = (const float*)d_in[3];
    const float* be_in = (const float*)d_in[4];
    const float* Wih0 = (const float*)d_in[5];
    const float* Whh0 = (const float*)d_in[6];
    const float* bih0 = (const float*)d_in[7];
    const float* bhh0 = (const float*)d_in[8];
    const float* Wih1 = (const float*)d_in[9];
    const float* Whh1 = (const float*)d_in[10];
    const float* bih1 = (const float*)d_in[11];
    const float* bhh1 = (const float*)d_in[12];
    const float* g_ln = (const float*)d_in[13];
    const float* be_ln = (const float*)d_in[14];
    const float* W_d1 = (const float*)d_in[15];
    const float* b_d1 = (const float*)d_in[16];
    const float* W_d2 = (const float*)d_in[17];
    const float* b_d2 = (const float*)d_in[18];
    const float* W_d3 = (const float*)d_in[19];
    const float* b_d3 = (const float*)d_in[20];
    float* out = (float*)d_out;

    // workspace layout (~197 MB): aux | Uhat | stats | hs0 | hlast
    char* w = (char*)d_ws;
    float* aux = (float*)w;               w += 512;
    u16* Uhat = (u16*)w;                  w += 512 * 32 * sizeof(u16);
    float2* stats = (float2*)w;           w += (size_t)B * T * sizeof(float2);
    u16* hs0 = (u16*)w;                   w += (size_t)B * T * H * sizeof(u16);
    u16* hlast = (u16*)w;

    prep_aux<<<1, 512, 0, stream>>>(W_in, b_in, g_in, be_in, Wih0, aux, Uhat);
    prep_stats<<<(B * T) / 256, 256, 0, stream>>>(x, aux, stats);
    lstm_rec_l1<<<B / 16, 512, 0, stream>>>(x, stats, Uhat, Whh0, bih0, bhh0, hs0);
    lstm_rec_l2<<<B / 16, 512, 0, stream>>>(Wih1, Whh1, bih1, bhh1, hs0, hlast);
    dense_head<<<B / 16, 256, 0, stream>>>(hlast, g_ln, be_ln, W_d1, b_d1, W_d2, b_d2,
                                           W_d3, b_d3, out);
}

// Round 8
// 512.984 us; speedup vs baseline: 2.9222x; 1.2568x over previous
//
#include <hip/hip_runtime.h>

#define DEV __device__ __forceinline__
typedef unsigned short u16;
typedef unsigned int u32;
typedef __bf16 bf16x8 __attribute__((ext_vector_type(8)));
typedef float f32x4 __attribute__((ext_vector_type(4)));

static constexpr int B = 8192, T = 90, F = 7, H = 128, NOUT = 30;
// logistic scale constants folded into weights: KS for sigmoid gates (i,f,o),
// KG for the tanh gate (g). Carry is kept in the scaled domain cs = KG * c.
#define KS (-1.44269504088896341f)
#define KG (-2.88539008177792681f)

DEV float fexp2(float x) { return __builtin_amdgcn_exp2f(x); }
DEV float frcp(float x) { return __builtin_amdgcn_rcpf(x); }
DEV float frsq(float x) { return __builtin_amdgcn_rsqf(x); }
DEV u16 f2bfbits(float f) { __bf16 b = (__bf16)f; return __builtin_bit_cast(u16, b); }
DEV float bfbits2f(u32 u) { return __builtin_bit_cast(float, u << 16); }
DEV u32 pk2(float a, float b) { return (u32)f2bfbits(a) | ((u32)f2bfbits(b) << 16); }

DEV float wave_sum(float v) {
#pragma unroll
    for (int m = 32; m; m >>= 1) v += __shfl_xor(v, m, 64);
    return v;
}

// ---------------------------------------------------------------------------
// prep_aux: one 512-thread block. R7: Uhat rows pre-scaled by the logistic
// constant of their gate, and the LSTM bias (bih0+bhh0) folded into column 9
// (the constant-1 slot of the augmented z) — l1 then needs no bias adds and
// no scale muls.
// ---------------------------------------------------------------------------
__global__ __launch_bounds__(512) void prep_aux(
    const float* __restrict__ W_in, const float* __restrict__ b_in,
    const float* __restrict__ g_in, const float* __restrict__ be_in,
    const float* __restrict__ Wih0, const float* __restrict__ bih0,
    const float* __restrict__ bhh0, float* __restrict__ aux, u16* __restrict__ Uhat) {
    const int tid = threadIdx.x;
    if (tid < 7) {
        float sm = 0.f, sp = 0.f;
        for (int h = 0; h < 128; ++h) { const float w = W_in[h * 7 + tid]; sm += w; sp += w * b_in[h]; }
        aux[tid] = sm * (1.f / 128.f); aux[64 + tid] = sp * (1.f / 128.f);
    } else if (tid < 56) {
        const int cd = tid - 7, cc = cd / 7, dd = cd % 7;
        float s = 0.f;
        for (int h = 0; h < 128; ++h) s += W_in[h * 7 + cc] * W_in[h * 7 + dd];
        aux[8 + cd] = s * (1.f / 128.f);
    } else if (tid == 56) {
        float s = 0.f; for (int h = 0; h < 128; ++h) s += b_in[h];
        aux[7] = s * (1.f / 128.f);
    } else if (tid == 57) {
        float s = 0.f; for (int h = 0; h < 128; ++h) s += b_in[h] * b_in[h];
        aux[72] = s * (1.f / 128.f);
    }
    float acc[10];
#pragma unroll
    for (int i = 0; i < 10; ++i) acc[i] = 0.f;
    const float* wr = Wih0 + (long)tid * 128;
    for (int h = 0; h < 128; ++h) {
        const float wv = wr[h], wg = wv * g_in[h];
#pragma unroll
        for (int cc = 0; cc < 7; ++cc) acc[cc] += wg * W_in[h * 7 + cc];
        acc[7] += wg * b_in[h]; acc[8] += wg; acc[9] += wv * be_in[h];
    }
    acc[9] += bih0[tid] + bhh0[tid];           // fold LSTM bias into const-1 column
    const float sg = ((tid >> 7) == 2) ? KG : KS;  // gate index = tid/128
    u16* dst = Uhat + tid * 32;
#pragma unroll
    for (int cc = 0; cc < 10; ++cc) dst[cc] = f2bfbits(acc[cc] * sg);
#pragma unroll
    for (int cc = 10; cc < 32; ++cc) dst[cc] = 0;
}

// ---------------------------------------------------------------------------
// prep_stats (unchanged)
// ---------------------------------------------------------------------------
__global__ __launch_bounds__(256) void prep_stats(
    const float* __restrict__ x, const float* __restrict__ aux,
    float2* __restrict__ stats) {
    __shared__ float sa[80];
    const int tid = threadIdx.x;
    if (tid < 80) sa[tid] = aux[tid];
    __syncthreads();
    const long idx = (long)blockIdx.x * 256 + tid;
    const float* xr = x + idx * 7;
    float xv[7];
#pragma unroll
    for (int cc = 0; cc < 7; ++cc) xv[cc] = xr[cc];
    float mu = sa[7];
#pragma unroll
    for (int cc = 0; cc < 7; ++cc) mu += sa[cc] * xv[cc];
    float q = sa[72];
#pragma unroll
    for (int cc = 0; cc < 7; ++cc) {
        float tacc = 2.f * sa[64 + cc];
#pragma unroll
        for (int dd = 0; dd < 7; ++dd) tacc += sa[8 + cc * 7 + dd] * xv[dd];
        q += xv[cc] * tacc;
    }
    const float rstd = frsq(q - mu * mu + 1e-5f);
    stats[idx] = make_float2(rstd, -rstd * mu);
}

// ---------------------------------------------------------------------------
// Gate math, scaled domain. ACC[g][r] = scaled pre-activation (weights carry
// the KS/KG factors; l1 also carries bias via Uhat col 9). CARR holds the
// scaled cell cs = KG*c. 10 transcendentals (floor), ~11 full-rate ops.
//   sigma(I) = rcp(1+exp2(KS*I));  tanh-gate via rg = rcp(1+exp2(KG*G)),
//   tgp = KG*tanh(G) = fma(rg, 2*KG, -KG);  cs' = sf*cs + si*tgp;
//   tanh(c') = 2*rcp(1+exp2(cs')) - 1;  h = so*tanh(c').
// ---------------------------------------------------------------------------
#define GATE1_R(ACC, CARR, SHROW, R)                                                    \
    {                                                                                   \
        const float si_ = frcp(1.f + fexp2(ACC[0][R]));                                 \
        const float sf_ = frcp(1.f + fexp2(ACC[1][R]));                                 \
        const float rg_ = frcp(1.f + fexp2(ACC[2][R]));                                 \
        const float so_ = frcp(1.f + fexp2(ACC[3][R]));                                 \
        const float tgp_ = __builtin_fmaf(rg_, 2.f * KG, -KG);                          \
        const float cs_ = __builtin_fmaf(sf_, CARR[R], si_ * tgp_);                     \
        CARR[R] = cs_;                                                                  \
        const float rc_ = frcp(1.f + fexp2(cs_));                                       \
        SHROW[hwbase + (R) * 8] = f2bfbits(__builtin_fmaf(so_ + so_, rc_, -so_));       \
    }

#define GATE2_R(ACC, CARR, SHROW, R)                                                    \
    {                                                                                   \
        const float si_ = frcp(1.f + fexp2(ACC[0][R] + bias[0]));                       \
        const float sf_ = frcp(1.f + fexp2(ACC[1][R] + bias[1]));                       \
        const float rg_ = frcp(1.f + fexp2(ACC[2][R] + bias[2]));                       \
        const float so_ = frcp(1.f + fexp2(ACC[3][R] + bias[3]));                       \
        const float tgp_ = __builtin_fmaf(rg_, 2.f * KG, -KG);                          \
        const float cs_ = __builtin_fmaf(sf_, CARR[R], si_ * tgp_);                     \
        CARR[R] = cs_;                                                                  \
        const float rc_ = frcp(1.f + fexp2(cs_));                                       \
        SHROW[hwbase + (R) * 8] = f2bfbits(__builtin_fmaf(so_ + so_, rc_, -so_));       \
    }

// ---------------------------------------------------------------------------
// Layer-1 LSTM (R1 structure, the 533.8 us best): parity-split LDS objects,
// time-unroll-2, 2 tiles of 16 rows, 512 thr, grid 256. R7 change: weights
// pre-scaled (Uhat in prep_aux, Whh0 at load), bias folded into Uhat col 9,
// lean scaled-domain gate math (GATE1_R).
// ---------------------------------------------------------------------------
__global__ __launch_bounds__(512, 2) void lstm_rec_l1(
    const float* __restrict__ x, const float2* __restrict__ stats,
    const u16* __restrict__ Uhat, const float* __restrict__ Whh,
    u16* __restrict__ hs) {
    __shared__ __align__(16) u16 s_zA[2][4][16][8];   // z parity A (t even)
    __shared__ __align__(16) u16 s_zB[2][4][16][8];   // z parity B (t odd)
    __shared__ __align__(16) u16 s_hA[2][16 * 128];   // h parity A (t even)
    __shared__ __align__(16) u16 s_hB[2][16 * 128];   // h parity B (t odd)

    const int tid = threadIdx.x;
    const int wave = tid >> 6, lane = tid & 63, quad = lane >> 4, n16 = lane & 15;
    const int b0 = blockIdx.x * 32;

    for (int i = tid; i < 2 * 4 * 16 * 8; i += 512) { ((u16*)s_zA)[i] = 0; ((u16*)s_zB)[i] = 0; }
    for (int i = tid; i < 2 * 16 * 128; i += 512) ((u16*)s_hB)[i] = 0;

    bf16x8 bU[4], bWhh[4][4];
#pragma unroll
    for (int g = 0; g < 4; ++g) {
        const float sg = (g == 2) ? KG : KS;
        const int wrow = g * 128 + 16 * wave + n16;
        bU[g] = *(const bf16x8*)&Uhat[wrow * 32 + quad * 8];
#pragma unroll
        for (int kk = 0; kk < 4; ++kk) {
            const float* ph = Whh + (long)wrow * 128 + kk * 32 + quad * 8;
            bf16x8 bh;
#pragma unroll
            for (int j = 0; j < 8; ++j) bh[j] = (__bf16)(ph[j] * sg);
            bWhh[g][kk] = bh;
        }
    }

    const f32x4 zero4 = {0.f, 0.f, 0.f, 0.f};
    f32x4 accA[4], accB[4];
    float c[2][4];
#pragma unroll
    for (int mt = 0; mt < 2; ++mt)
#pragma unroll
        for (int r = 0; r < 4; ++r) c[mt][r] = 0.f;

    // staging: 8 lanes/wave, 64 units cover 32 rows x 2 kk8-chunks
    const bool stager = (lane < 8);
    const int tau = wave * 8 + lane;
    const int srow = tau & 31, skk8 = tau >> 5;
    const int smt = srow >> 4, sm = srow & 15;
    const long srowg = (long)(b0 + srow) * T;

    // per-tile flush map (tid<256): 16 rows x 16 col-chunks
    const int fm = tid & 15, fkk8 = (tid >> 4) & 15;
    const int fldsoff = (fkk8 * 16 + fm) * 8;
    const int fgcol = fkk8 * 8;

    const int hwbase = (2 * wave + (n16 >> 3)) * 128 + quad * 32 + (n16 & 7);

    __syncthreads();  // zero-init visible before prologue staging stores

    if (stager) {  // stage z(0) -> zA
        const float2 st0 = stats[srowg];
        u32 p0, p1, p2, p3;
        if (skk8 == 0) {
            const float* xp = x + srowg * 7;
            const float rs = st0.x;
            p0 = pk2(rs * xp[0], rs * xp[1]); p1 = pk2(rs * xp[2], rs * xp[3]);
            p2 = pk2(rs * xp[4], rs * xp[5]); p3 = pk2(rs * xp[6], rs);
        } else { p0 = pk2(st0.y, 1.f); p1 = 0; p2 = 0; p3 = 0; }
        *(uint4*)&s_zA[smt][skk8][sm][0] = (uint4){p0, p1, p2, p3};
    }
    __syncthreads();

#define L1_CH(AZ, AH, G, OUT)                                                           \
    {                                                                                   \
        f32x4 a_ = __builtin_amdgcn_mfma_f32_16x16x32_bf16(AZ, bU[G], zero4, 0, 0, 0);  \
        a_ = __builtin_amdgcn_mfma_f32_16x16x32_bf16(AH[0], bWhh[G][0], a_, 0, 0, 0);   \
        a_ = __builtin_amdgcn_mfma_f32_16x16x32_bf16(AH[1], bWhh[G][1], a_, 0, 0, 0);   \
        a_ = __builtin_amdgcn_mfma_f32_16x16x32_bf16(AH[2], bWhh[G][2], a_, 0, 0, 0);   \
        a_ = __builtin_amdgcn_mfma_f32_16x16x32_bf16(AH[3], bWhh[G][3], a_, 0, 0, 0);   \
        OUT = a_;                                                                       \
    }

#define L1_STEP(TT, SZR, SZW, SHR, SHW)                                                 \
    {                                                                                   \
        const int t_ = (TT);                                                            \
        const bool hasPre = stager && (t_ + 1 < T);                                     \
        float2 nst_ = {};                                                               \
        float nx_[7];                                                                   \
        if (hasPre) {                                                                   \
            nst_ = stats[srowg + t_ + 1];                                               \
            if (skk8 == 0) {                                                            \
                const float* xp_ = x + (srowg + t_ + 1) * 7;                            \
                _Pragma("unroll") for (int j = 0; j < 7; ++j) nx_[j] = xp_[j];          \
            }                                                                           \
        }                                                                               \
        if (t_ > 0 && tid < 512) {  /* flush h(t-1) from the read-side buffer */        \
            if (tid < 256) {                                                            \
                const uint4 hv0 = *(const uint4*)&SHR[0][fldsoff];                      \
                *(uint4*)(hs + (((size_t)(b0 + fm) * T) + (t_ - 1)) * 128 + fgcol) = hv0; \
            } else {                                                                    \
                const uint4 hv1 = *(const uint4*)&SHR[1][fldsoff];                      \
                *(uint4*)(hs + (((size_t)(b0 + 16 + fm) * T) + (t_ - 1)) * 128 + fgcol) = hv1; \
            }                                                                           \
        }                                                                               \
        bf16x8 az0, ah0[4];                                                             \
        az0 = *(const bf16x8*)&SZR[0][quad][n16][0];                                    \
        _Pragma("unroll") for (int kk = 0; kk < 4; ++kk)                                \
            ah0[kk] = *(const bf16x8*)&SHR[0][((kk * 4 + quad) * 16 + n16) * 8];        \
        f32x4 acc0[4], acc1[4];                                                         \
        L1_CH(az0, ah0, 0, acc0[0])                                                     \
        L1_CH(az0, ah0, 1, acc0[1])                                                     \
        L1_CH(az0, ah0, 2, acc0[2])                                                     \
        L1_CH(az0, ah0, 3, acc0[3])                                                     \
        bf16x8 az1, ah1[4];                                                             \
        az1 = *(const bf16x8*)&SZR[1][quad][n16][0];                                    \
        _Pragma("unroll") for (int kk = 0; kk < 4; ++kk)                                \
            ah1[kk] = *(const bf16x8*)&SHR[1][((kk * 4 + quad) * 16 + n16) * 8];        \
        L1_CH(az1, ah1, 0, acc1[0])                                                     \
        GATE1_R(acc0, c[0], SHW[0], 0)                                                  \
        L1_CH(az1, ah1, 1, acc1[1])                                                     \
        GATE1_R(acc0, c[0], SHW[0], 1)                                                  \
        L1_CH(az1, ah1, 2, acc1[2])                                                     \
        GATE1_R(acc0, c[0], SHW[0], 2)                                                  \
        L1_CH(az1, ah1, 3, acc1[3])                                                     \
        GATE1_R(acc0, c[0], SHW[0], 3)                                                  \
        GATE1_R(acc1, c[1], SHW[1], 0)                                                  \
        GATE1_R(acc1, c[1], SHW[1], 1)                                                  \
        GATE1_R(acc1, c[1], SHW[1], 2)                                                  \
        GATE1_R(acc1, c[1], SHW[1], 3)                                                  \
        if (hasPre) {  /* commit z(t+1) */                                              \
            u32 p0_, p1_, p2_, p3_;                                                     \
            if (skk8 == 0) {                                                            \
                const float rs_ = nst_.x;                                               \
                p0_ = pk2(rs_ * nx_[0], rs_ * nx_[1]); p1_ = pk2(rs_ * nx_[2], rs_ * nx_[3]); \
                p2_ = pk2(rs_ * nx_[4], rs_ * nx_[5]); p3_ = pk2(rs_ * nx_[6], rs_);    \
            } else { p0_ = pk2(nst_.y, 1.f); p1_ = 0; p2_ = 0; p3_ = 0; }               \
            *(uint4*)&SZW[smt][skk8][sm][0] = (uint4){p0_, p1_, p2_, p3_};              \
        }                                                                               \
        __syncthreads();                                                                \
    }

#pragma unroll 1
    for (int t = 0; t < T; t += 2) {
        L1_STEP(t, s_zA, s_zB, s_hB, s_hA)        // even t: read z A / h B, write h A
        L1_STEP(t + 1, s_zB, s_zA, s_hA, s_hB)    // odd t: roles swapped
    }
#undef L1_STEP
#undef L1_CH
    {  // epilogue: h(T-1) was written at odd parity -> s_hB
        const int ftile = tid >> 8, finner = tid & 255;
        const int efm = finner & 15, efkk8 = finner >> 4;
        const uint4 hv = *(const uint4*)&s_hB[ftile][(efkk8 * 16 + efm) * 8];
        *(uint4*)(hs + ((size_t)(b0 + ftile * 16 + efm) * T + (T - 1)) * 128 + efkk8 * 8) = hv;
    }
}

// ---------------------------------------------------------------------------
// Layer-2 LSTM (R1 structure). R7: weights pre-scaled at load, bias pre-scaled,
// lean gate math (GATE2_R keeps the 4 bias adds; bias-in-C would exceed the
// 128-reg cap of (512,2)).
// ---------------------------------------------------------------------------
__global__ __launch_bounds__(512, 2) void lstm_rec_l2(
    const float* __restrict__ Wih, const float* __restrict__ Whh,
    const float* __restrict__ bih, const float* __restrict__ bhh,
    const u16* __restrict__ xin, u16* __restrict__ hlast) {
    __shared__ __align__(16) u16 s_xA[2][16 * 128];
    __shared__ __align__(16) u16 s_xB[2][16 * 128];
    __shared__ __align__(16) u16 s_hA[2][16 * 128];
    __shared__ __align__(16) u16 s_hB[2][16 * 128];

    const int tid = threadIdx.x;
    const int wave = tid >> 6, lane = tid & 63, quad = lane >> 4, n16 = lane & 15;
    const int b0 = blockIdx.x * 32;

    for (int i = tid; i < 2 * 16 * 128; i += 512) ((u16*)s_hB)[i] = 0;

    bf16x8 bWih[4][4], bWhh[4][4];
    float bias[4];
#pragma unroll
    for (int g = 0; g < 4; ++g) {
        const float sg = (g == 2) ? KG : KS;
        const int wrow = g * 128 + 16 * wave + n16;
        bias[g] = (bih[wrow] + bhh[wrow]) * sg;
#pragma unroll
        for (int kk = 0; kk < 4; ++kk) {
            const float* pi = Wih + (long)wrow * 128 + kk * 32 + quad * 8;
            const float* ph = Whh + (long)wrow * 128 + kk * 32 + quad * 8;
            bf16x8 bi, bh;
#pragma unroll
            for (int j = 0; j < 8; ++j) { bi[j] = (__bf16)(pi[j] * sg); bh[j] = (__bf16)(ph[j] * sg); }
            bWih[g][kk] = bi; bWhh[g][kk] = bh;
        }
    }

    const f32x4 zero4 = {0.f, 0.f, 0.f, 0.f};
    f32x4 accA[4], accB[4];
    float c[2][4];
#pragma unroll
    for (int mt = 0; mt < 2; ++mt)
#pragma unroll
        for (int r = 0; r < 4; ++r) c[mt][r] = 0.f;

    const int stile = tid >> 8, sinner = tid & 255;
    const int ssm = sinner & 15, sskk8 = sinner >> 4;
    const u16* gsrc = xin + (size_t)(b0 + stile * 16 + ssm) * T * 128 + sskk8 * 8;
    const int soff = sinner * 8;

    const int hwbase = (2 * wave + (n16 >> 3)) * 128 + quad * 32 + (n16 & 7);

    {  // prologue stage x(0) -> xA
        const uint4 v = *(const uint4*)gsrc;
        *(uint4*)&s_xA[stile][soff] = v;
    }
    __syncthreads();

#define L2_CH(AX, AH, G, OUT)                                                           \
    {                                                                                   \
        f32x4 a_ = __builtin_amdgcn_mfma_f32_16x16x32_bf16(AX[0], bWih[G][0], zero4, 0, 0, 0); \
        a_ = __builtin_amdgcn_mfma_f32_16x16x32_bf16(AH[0], bWhh[G][0], a_, 0, 0, 0);   \
        a_ = __builtin_amdgcn_mfma_f32_16x16x32_bf16(AX[1], bWih[G][1], a_, 0, 0, 0);   \
        a_ = __builtin_amdgcn_mfma_f32_16x16x32_bf16(AH[1], bWhh[G][1], a_, 0, 0, 0);   \
        a_ = __builtin_amdgcn_mfma_f32_16x16x32_bf16(AX[2], bWih[G][2], a_, 0, 0, 0);   \
        a_ = __builtin_amdgcn_mfma_f32_16x16x32_bf16(AH[2], bWhh[G][2], a_, 0, 0, 0);   \
        a_ = __builtin_amdgcn_mfma_f32_16x16x32_bf16(AX[3], bWih[G][3], a_, 0, 0, 0);   \
        a_ = __builtin_amdgcn_mfma_f32_16x16x32_bf16(AH[3], bWhh[G][3], a_, 0, 0, 0);   \
        OUT = a_;                                                                       \
    }

#define L2_STEP(TT, SXR, SXW, SHR, SHW)                                                 \
    {                                                                                   \
        const int t_ = (TT);                                                            \
        const bool hasPre = (t_ + 1 < T);                                               \
        uint4 pre = {};                                                                 \
        if (hasPre) pre = *(const uint4*)(gsrc + (size_t)(t_ + 1) * 128);               \
        bf16x8 aln0[4], ah0[4];                                                         \
        _Pragma("unroll") for (int kk = 0; kk < 4; ++kk) {                              \
            const int ro = (kk * 4 + quad) * 128 + n16 * 8;                             \
            aln0[kk] = *(const bf16x8*)&SXR[0][ro];                                     \
            ah0[kk] = *(const bf16x8*)&SHR[0][ro];                                      \
        }                                                                               \
        f32x4 acc0[4], acc1[4];                                                         \
        L2_CH(aln0, ah0, 0, acc0[0])                                                    \
        L2_CH(aln0, ah0, 1, acc0[1])                                                    \
        L2_CH(aln0, ah0, 2, acc0[2])                                                    \
        L2_CH(aln0, ah0, 3, acc0[3])                                                    \
        bf16x8 aln1[4], ah1[4];                                                         \
        _Pragma("unroll") for (int kk = 0; kk < 4; ++kk) {                              \
            const int ro = (kk * 4 + quad) * 128 + n16 * 8;                             \
            aln1[kk] = *(const bf16x8*)&SXR[1][ro];                                     \
            ah1[kk] = *(const bf16x8*)&SHR[1][ro];                                      \
        }                                                                               \
        L2_CH(aln1, ah1, 0, acc1[0])                                                    \
        GATE2_R(acc0, c[0], SHW[0], 0)                                                  \
        L2_CH(aln1, ah1, 1, acc1[1])                                                    \
        GATE2_R(acc0, c[0], SHW[0], 1)                                                  \
        L2_CH(aln1, ah1, 2, acc1[2])                                                    \
        GATE2_R(acc0, c[0], SHW[0], 2)                                                  \
        L2_CH(aln1, ah1, 3, acc1[3])                                                    \
        GATE2_R(acc0, c[0], SHW[0], 3)                                                  \
        GATE2_R(acc1, c[1], SHW[1], 0)                                                  \
        GATE2_R(acc1, c[1], SHW[1], 1)                                                  \
        GATE2_R(acc1, c[1], SHW[1], 2)                                                  \
        GATE2_R(acc1, c[1], SHW[1], 3)                                                  \
        if (hasPre) *(uint4*)&SXW[stile][soff] = pre;                                   \
        __syncthreads();                                                                \
    }

#pragma unroll 1
    for (int t = 0; t < T; t += 2) {
        L2_STEP(t, s_xA, s_xB, s_hB, s_hA)        // even t
        L2_STEP(t + 1, s_xB, s_xA, s_hA, s_hB)    // odd t
    }
#undef L2_STEP
#undef L2_CH
    {  // h(T-1) written at odd parity -> s_hB
        const uint4 hv = *(const uint4*)&s_hB[stile][(sskk8 * 16 + ssm) * 8];
        *(uint4*)(hlast + (size_t)(b0 + stile * 16 + ssm) * 128 + sskk8 * 8) = hv;
    }
}

// ---------------------------------------------------------------------------
// Head: 4 rows per wave, 16 rows per block, grid 512. (unchanged)
// ---------------------------------------------------------------------------
__global__ __launch_bounds__(256) void dense_head(
    const u16* __restrict__ hlast, const float* __restrict__ g_ln,
    const float* __restrict__ be_ln, const float* __restrict__ W_d1,
    const float* __restrict__ b_d1, const float* __restrict__ W_d2,
    const float* __restrict__ b_d2, const float* __restrict__ W_d3,
    const float* __restrict__ b_d3, float* __restrict__ out) {
    __shared__ float s_ln[16][128];
    __shared__ float s_d1[16][128];
    __shared__ float s_d2[16][64];
    const int wave = threadIdx.x >> 6, lane = threadIdx.x & 63;
    const long base = (long)blockIdx.x * 16;
    const int R = wave * 4;

#pragma unroll
    for (int rr = 0; rr < 4; ++rr) {
        const long row = base + R + rr;
        const u32 packed = ((const u32*)hlast)[row * 64 + lane];
        float v0 = bfbits2f(packed & 0xffffu), v1 = bfbits2f(packed >> 16);
        const float s = wave_sum(v0 + v1);
        const float q = wave_sum(v0 * v0 + v1 * v1);
        const float mu = s * (1.f / 128.f);
        const float rstd = frsq(q * (1.f / 128.f) - mu * mu + 1e-5f);
        const int h0 = 2 * lane;
        s_ln[R + rr][h0] = (v0 - mu) * rstd * g_ln[h0] + be_ln[h0];
        s_ln[R + rr][h0 + 1] = (v1 - mu) * rstd * g_ln[h0 + 1] + be_ln[h0 + 1];
    }
    __syncthreads();

#pragma unroll
    for (int half = 0; half < 2; ++half) {
        const int o = lane + 64 * half;
        float a[4] = {b_d1[o], b_d1[o], b_d1[o], b_d1[o]};
        const float4* wr = (const float4*)(W_d1 + (long)o * 128);
#pragma unroll 8
        for (int k = 0; k < 32; ++k) {
            const float4 wv = wr[k];
#pragma unroll
            for (int rr = 0; rr < 4; ++rr) {
                const float4 xv = ((const float4*)s_ln[R + rr])[k];
                a[rr] += wv.x * xv.x + wv.y * xv.y + wv.z * xv.z + wv.w * xv.w;
            }
        }
#pragma unroll
        for (int rr = 0; rr < 4; ++rr) s_d1[R + rr][o] = fmaxf(a[rr], 0.f);
    }
    __syncthreads();

    {
        float a[4] = {b_d2[lane], b_d2[lane], b_d2[lane], b_d2[lane]};
        const float4* wr = (const float4*)(W_d2 + (long)lane * 128);
#pragma unroll 8
        for (int k = 0; k < 32; ++k) {
            const float4 wv = wr[k];
#pragma unroll
            for (int rr = 0; rr < 4; ++rr) {
                const float4 xv = ((const float4*)s_d1[R + rr])[k];
                a[rr] += wv.x * xv.x + wv.y * xv.y + wv.z * xv.z + wv.w * xv.w;
            }
        }
#pragma unroll
        for (int rr = 0; rr < 4; ++rr) s_d2[R + rr][lane] = fmaxf(a[rr], 0.f);
    }
    __syncthreads();

    if (lane < NOUT) {
        float a[4] = {b_d3[lane], b_d3[lane], b_d3[lane], b_d3[lane]};
        const float4* wr = (const float4*)(W_d3 + (long)lane * 64);
#pragma unroll
        for (int k = 0; k < 16; ++k) {
            const float4 wv = wr[k];
#pragma unroll
            for (int rr = 0; rr < 4; ++rr) {
                const float4 xv = ((const float4*)s_d2[R + rr])[k];
                a[rr] += wv.x * xv.x + wv.y * xv.y + wv.z * xv.z + wv.w * xv.w;
            }
        }
#pragma unroll
        for (int rr = 0; rr < 4; ++rr) out[(base + R + rr) * NOUT + lane] = a[rr];
    }
}

// ---------------------------------------------------------------------------
extern "C" void kernel_launch(void* const* d_in, const int* in_sizes, int n_in,
                              void* d_out, int out_size, void* d_ws, size_t ws_size,
                              hipStream_t stream) {
    const float* x = (const float*)d_in[0];
    const float* W_in = (const float*)d_in[1];
    const float* b_in = (const float*)d_in[2];
    const float* g_in = (const float*)d_in[3];
    const float* be_in = (const float*)d_in[4];
    const float* Wih0 = (const float*)d_in[5];
    const float* Whh0 = (const float*)d_in[6];
    const float* bih0 = (const float*)d_in[7];
    const float* bhh0 = (const float*)d_in[8];
    const float* Wih1 = (const float*)d_in[9];
    const float* Whh1 = (const float*)d_in[10];
    const float* bih1 = (const float*)d_in[11];
    const float* bhh1 = (const float*)d_in[12];
    const float* g_ln = (const float*)d_in[13];
    const float* be_ln = (const float*)d_in[14];
    const float* W_d1 = (const float*)d_in[15];
    const float* b_d1 = (const float*)d_in[16];
    const float* W_d2 = (const float*)d_in[17];
    const float* b_d2 = (const float*)d_in[18];
    const float* W_d3 = (const float*)d_in[19];
    const float* b_d3 = (const float*)d_in[20];
    float* out = (float*)d_out;

    // workspace layout (~197 MB): aux | Uhat | stats | hs0 | hlast
    char* w = (char*)d_ws;
    float* aux = (float*)w;               w += 512;
    u16* Uhat = (u16*)w;                  w += 512 * 32 * sizeof(u16);
    float2* stats = (float2*)w;           w += (size_t)B * T * sizeof(float2);
    u16* hs0 = (u16*)w;                   w += (size_t)B * T * H * sizeof(u16);
    u16* hlast = (u16*)w;

    prep_aux<<<1, 512, 0, stream>>>(W_in, b_in, g_in, be_in, Wih0, bih0, bhh0, aux, Uhat);
    prep_stats<<<(B * T) / 256, 256, 0, stream>>>(x, aux, stats);
    lstm_rec_l1<<<B / 32, 512, 0, stream>>>(x, stats, Uhat, Whh0, hs0);
    lstm_rec_l2<<<B / 32, 512, 0, stream>>>(Wih1, Whh1, bih1, bhh1, hs0, hlast);
    dense_head<<<B / 16, 256, 0, stream>>>(hlast, g_ln, be_ln, W_d1, b_d1, W_d2, b_d2,
                                           W_d3, b_d3, out);
}

// Round 9
// 503.195 us; speedup vs baseline: 2.9790x; 1.0195x over previous
//
#include <hip/hip_runtime.h>

#define DEV __device__ __forceinline__
typedef unsigned short u16;
typedef unsigned int u32;
typedef __bf16 bf16x8 __attribute__((ext_vector_type(8)));
typedef float f32x4 __attribute__((ext_vector_type(4)));

static constexpr int B = 8192, T = 90, F = 7, H = 128, NOUT = 30;
// logistic scale constants folded into weights: KS for sigmoid gates (i,f,o),
// KG for the tanh gate (g). Carry is kept in the scaled domain cs = KG * c.
#define KS (-1.44269504088896341f)
#define KG (-2.88539008177792681f)

DEV float fexp2(float x) { return __builtin_amdgcn_exp2f(x); }
DEV float frcp(float x) { return __builtin_amdgcn_rcpf(x); }
DEV float frsq(float x) { return __builtin_amdgcn_rsqf(x); }
DEV u16 f2bfbits(float f) { __bf16 b = (__bf16)f; return __builtin_bit_cast(u16, b); }
DEV float bfbits2f(u32 u) { return __builtin_bit_cast(float, u << 16); }
DEV u32 pk2(float a, float b) { return (u32)f2bfbits(a) | ((u32)f2bfbits(b) << 16); }

DEV float wave_sum(float v) {
#pragma unroll
    for (int m = 32; m; m >>= 1) v += __shfl_xor(v, m, 64);
    return v;
}

// ---------------------------------------------------------------------------
// prep_aux: one 512-thread block. Uhat rows pre-scaled by the logistic
// constant of their gate; LSTM bias folded into column 9 (const-1 slot).
// ---------------------------------------------------------------------------
__global__ __launch_bounds__(512) void prep_aux(
    const float* __restrict__ W_in, const float* __restrict__ b_in,
    const float* __restrict__ g_in, const float* __restrict__ be_in,
    const float* __restrict__ Wih0, const float* __restrict__ bih0,
    const float* __restrict__ bhh0, float* __restrict__ aux, u16* __restrict__ Uhat) {
    const int tid = threadIdx.x;
    if (tid < 7) {
        float sm = 0.f, sp = 0.f;
        for (int h = 0; h < 128; ++h) { const float w = W_in[h * 7 + tid]; sm += w; sp += w * b_in[h]; }
        aux[tid] = sm * (1.f / 128.f); aux[64 + tid] = sp * (1.f / 128.f);
    } else if (tid < 56) {
        const int cd = tid - 7, cc = cd / 7, dd = cd % 7;
        float s = 0.f;
        for (int h = 0; h < 128; ++h) s += W_in[h * 7 + cc] * W_in[h * 7 + dd];
        aux[8 + cd] = s * (1.f / 128.f);
    } else if (tid == 56) {
        float s = 0.f; for (int h = 0; h < 128; ++h) s += b_in[h];
        aux[7] = s * (1.f / 128.f);
    } else if (tid == 57) {
        float s = 0.f; for (int h = 0; h < 128; ++h) s += b_in[h] * b_in[h];
        aux[72] = s * (1.f / 128.f);
    }
    float acc[10];
#pragma unroll
    for (int i = 0; i < 10; ++i) acc[i] = 0.f;
    const float* wr = Wih0 + (long)tid * 128;
    for (int h = 0; h < 128; ++h) {
        const float wv = wr[h], wg = wv * g_in[h];
#pragma unroll
        for (int cc = 0; cc < 7; ++cc) acc[cc] += wg * W_in[h * 7 + cc];
        acc[7] += wg * b_in[h]; acc[8] += wg; acc[9] += wv * be_in[h];
    }
    acc[9] += bih0[tid] + bhh0[tid];           // fold LSTM bias into const-1 column
    const float sg = ((tid >> 7) == 2) ? KG : KS;  // gate index = tid/128
    u16* dst = Uhat + tid * 32;
#pragma unroll
    for (int cc = 0; cc < 10; ++cc) dst[cc] = f2bfbits(acc[cc] * sg);
#pragma unroll
    for (int cc = 10; cc < 32; ++cc) dst[cc] = 0;
}

// ---------------------------------------------------------------------------
// prep_stats (unchanged)
// ---------------------------------------------------------------------------
__global__ __launch_bounds__(256) void prep_stats(
    const float* __restrict__ x, const float* __restrict__ aux,
    float2* __restrict__ stats) {
    __shared__ float sa[80];
    const int tid = threadIdx.x;
    if (tid < 80) sa[tid] = aux[tid];
    __syncthreads();
    const long idx = (long)blockIdx.x * 256 + tid;
    const float* xr = x + idx * 7;
    float xv[7];
#pragma unroll
    for (int cc = 0; cc < 7; ++cc) xv[cc] = xr[cc];
    float mu = sa[7];
#pragma unroll
    for (int cc = 0; cc < 7; ++cc) mu += sa[cc] * xv[cc];
    float q = sa[72];
#pragma unroll
    for (int cc = 0; cc < 7; ++cc) {
        float tacc = 2.f * sa[64 + cc];
#pragma unroll
        for (int dd = 0; dd < 7; ++dd) tacc += sa[8 + cc * 7 + dd] * xv[dd];
        q += xv[cc] * tacc;
    }
    const float rstd = frsq(q - mu * mu + 1e-5f);
    stats[idx] = make_float2(rstd, -rstd * mu);
}

// ---------------------------------------------------------------------------
// Gate math, scaled domain, common-denominator form (R8): 5 exp2 + 2 rcp per
// element (was 5+5). ACC[g][r] = scaled pre-activation INCLUDING bias (l1 via
// Uhat col 9, l2 via MFMA C-init). CARR holds cs = KG*c.
//   cs' = [cs(1+ei)(1+eg) + KG(1-eg)(1+ef)] / [(1+ei)(1+ef)(1+eg)]
//   h   = (1-ec) / [(1+ec)(1+eo)]          (ec = exp2(cs'))
// ---------------------------------------------------------------------------
#define GATE_R(ACC, CARR, SHROW, R)                                                     \
    {                                                                                   \
        const float ei_ = fexp2(ACC[0][R]);                                             \
        const float ef_ = fexp2(ACC[1][R]);                                             \
        const float eg_ = fexp2(ACC[2][R]);                                             \
        const float eo_ = fexp2(ACC[3][R]);                                             \
        const float bf_ = 1.f + ef_;                                                    \
        const float t1_ = (1.f + ei_) * (1.f + eg_);                                    \
        const float t2_ = __builtin_fmaf(eg_, -KG, KG);                                 \
        const float num_ = __builtin_fmaf(CARR[R], t1_, t2_ * bf_);                     \
        const float cs_ = num_ * frcp(t1_ * bf_);                                       \
        CARR[R] = cs_;                                                                  \
        const float ec_ = fexp2(cs_);                                                   \
        const float hd_ = (1.f + ec_) * (1.f + eo_);                                    \
        SHROW[hwbase + (R) * 8] = f2bfbits((1.f - ec_) * frcp(hd_));                    \
    }

// ---------------------------------------------------------------------------
// Layer-1 LSTM (R1 structure): parity-split LDS, time-unroll-2, 2 tiles of 16
// rows, 512 thr, grid 256. Weights pre-scaled; bias in Uhat col 9; R8 gate.
// ---------------------------------------------------------------------------
__global__ __launch_bounds__(512, 2) void lstm_rec_l1(
    const float* __restrict__ x, const float2* __restrict__ stats,
    const u16* __restrict__ Uhat, const float* __restrict__ Whh,
    u16* __restrict__ hs) {
    __shared__ __align__(16) u16 s_zA[2][4][16][8];   // z parity A (t even)
    __shared__ __align__(16) u16 s_zB[2][4][16][8];   // z parity B (t odd)
    __shared__ __align__(16) u16 s_hA[2][16 * 128];   // h parity A (t even)
    __shared__ __align__(16) u16 s_hB[2][16 * 128];   // h parity B (t odd)

    const int tid = threadIdx.x;
    const int wave = tid >> 6, lane = tid & 63, quad = lane >> 4, n16 = lane & 15;
    const int b0 = blockIdx.x * 32;

    for (int i = tid; i < 2 * 4 * 16 * 8; i += 512) { ((u16*)s_zA)[i] = 0; ((u16*)s_zB)[i] = 0; }
    for (int i = tid; i < 2 * 16 * 128; i += 512) ((u16*)s_hB)[i] = 0;

    bf16x8 bU[4], bWhh[4][4];
#pragma unroll
    for (int g = 0; g < 4; ++g) {
        const float sg = (g == 2) ? KG : KS;
        const int wrow = g * 128 + 16 * wave + n16;
        bU[g] = *(const bf16x8*)&Uhat[wrow * 32 + quad * 8];
#pragma unroll
        for (int kk = 0; kk < 4; ++kk) {
            const float* ph = Whh + (long)wrow * 128 + kk * 32 + quad * 8;
            bf16x8 bh;
#pragma unroll
            for (int j = 0; j < 8; ++j) bh[j] = (__bf16)(ph[j] * sg);
            bWhh[g][kk] = bh;
        }
    }

    const f32x4 zero4 = {0.f, 0.f, 0.f, 0.f};
    f32x4 accA[4], accB[4];
    float c[2][4];
#pragma unroll
    for (int mt = 0; mt < 2; ++mt)
#pragma unroll
        for (int r = 0; r < 4; ++r) c[mt][r] = 0.f;

    // staging: 8 lanes/wave, 64 units cover 32 rows x 2 kk8-chunks
    const bool stager = (lane < 8);
    const int tau = wave * 8 + lane;
    const int srow = tau & 31, skk8 = tau >> 5;
    const int smt = srow >> 4, sm = srow & 15;
    const long srowg = (long)(b0 + srow) * T;

    // per-tile flush map (tid<256): 16 rows x 16 col-chunks
    const int fm = tid & 15, fkk8 = (tid >> 4) & 15;
    const int fldsoff = (fkk8 * 16 + fm) * 8;
    const int fgcol = fkk8 * 8;

    const int hwbase = (2 * wave + (n16 >> 3)) * 128 + quad * 32 + (n16 & 7);

    __syncthreads();  // zero-init visible before prologue staging stores

    if (stager) {  // stage z(0) -> zA
        const float2 st0 = stats[srowg];
        u32 p0, p1, p2, p3;
        if (skk8 == 0) {
            const float* xp = x + srowg * 7;
            const float rs = st0.x;
            p0 = pk2(rs * xp[0], rs * xp[1]); p1 = pk2(rs * xp[2], rs * xp[3]);
            p2 = pk2(rs * xp[4], rs * xp[5]); p3 = pk2(rs * xp[6], rs);
        } else { p0 = pk2(st0.y, 1.f); p1 = 0; p2 = 0; p3 = 0; }
        *(uint4*)&s_zA[smt][skk8][sm][0] = (uint4){p0, p1, p2, p3};
    }
    __syncthreads();

#define L1_CH(AZ, AH, G, OUT)                                                           \
    {                                                                                   \
        f32x4 a_ = __builtin_amdgcn_mfma_f32_16x16x32_bf16(AZ, bU[G], zero4, 0, 0, 0);  \
        a_ = __builtin_amdgcn_mfma_f32_16x16x32_bf16(AH[0], bWhh[G][0], a_, 0, 0, 0);   \
        a_ = __builtin_amdgcn_mfma_f32_16x16x32_bf16(AH[1], bWhh[G][1], a_, 0, 0, 0);   \
        a_ = __builtin_amdgcn_mfma_f32_16x16x32_bf16(AH[2], bWhh[G][2], a_, 0, 0, 0);   \
        a_ = __builtin_amdgcn_mfma_f32_16x16x32_bf16(AH[3], bWhh[G][3], a_, 0, 0, 0);   \
        OUT = a_;                                                                       \
    }

#define L1_STEP(TT, SZR, SZW, SHR, SHW)                                                 \
    {                                                                                   \
        const int t_ = (TT);                                                            \
        const bool hasPre = stager && (t_ + 1 < T);                                     \
        float2 nst_ = {};                                                               \
        float nx_[7];                                                                   \
        if (hasPre) {                                                                   \
            nst_ = stats[srowg + t_ + 1];                                               \
            if (skk8 == 0) {                                                            \
                const float* xp_ = x + (srowg + t_ + 1) * 7;                            \
                _Pragma("unroll") for (int j = 0; j < 7; ++j) nx_[j] = xp_[j];          \
            }                                                                           \
        }                                                                               \
        if (t_ > 0 && tid < 512) {  /* flush h(t-1) from the read-side buffer */        \
            if (tid < 256) {                                                            \
                const uint4 hv0 = *(const uint4*)&SHR[0][fldsoff];                      \
                *(uint4*)(hs + (((size_t)(b0 + fm) * T) + (t_ - 1)) * 128 + fgcol) = hv0; \
            } else {                                                                    \
                const uint4 hv1 = *(const uint4*)&SHR[1][fldsoff];                      \
                *(uint4*)(hs + (((size_t)(b0 + 16 + fm) * T) + (t_ - 1)) * 128 + fgcol) = hv1; \
            }                                                                           \
        }                                                                               \
        bf16x8 az0, ah0[4];                                                             \
        az0 = *(const bf16x8*)&SZR[0][quad][n16][0];                                    \
        _Pragma("unroll") for (int kk = 0; kk < 4; ++kk)                                \
            ah0[kk] = *(const bf16x8*)&SHR[0][((kk * 4 + quad) * 16 + n16) * 8];        \
        f32x4 acc0[4], acc1[4];                                                         \
        L1_CH(az0, ah0, 0, acc0[0])                                                     \
        L1_CH(az0, ah0, 1, acc0[1])                                                     \
        L1_CH(az0, ah0, 2, acc0[2])                                                     \
        L1_CH(az0, ah0, 3, acc0[3])                                                     \
        bf16x8 az1, ah1[4];                                                             \
        az1 = *(const bf16x8*)&SZR[1][quad][n16][0];                                    \
        _Pragma("unroll") for (int kk = 0; kk < 4; ++kk)                                \
            ah1[kk] = *(const bf16x8*)&SHR[1][((kk * 4 + quad) * 16 + n16) * 8];        \
        L1_CH(az1, ah1, 0, acc1[0])                                                     \
        GATE_R(acc0, c[0], SHW[0], 0)                                                   \
        L1_CH(az1, ah1, 1, acc1[1])                                                     \
        GATE_R(acc0, c[0], SHW[0], 1)                                                   \
        L1_CH(az1, ah1, 2, acc1[2])                                                     \
        GATE_R(acc0, c[0], SHW[0], 2)                                                   \
        L1_CH(az1, ah1, 3, acc1[3])                                                     \
        GATE_R(acc0, c[0], SHW[0], 3)                                                   \
        GATE_R(acc1, c[1], SHW[1], 0)                                                   \
        GATE_R(acc1, c[1], SHW[1], 1)                                                   \
        GATE_R(acc1, c[1], SHW[1], 2)                                                   \
        GATE_R(acc1, c[1], SHW[1], 3)                                                   \
        if (hasPre) {  /* commit z(t+1) */                                              \
            u32 p0_, p1_, p2_, p3_;                                                     \
            if (skk8 == 0) {                                                            \
                const float rs_ = nst_.x;                                               \
                p0_ = pk2(rs_ * nx_[0], rs_ * nx_[1]); p1_ = pk2(rs_ * nx_[2], rs_ * nx_[3]); \
                p2_ = pk2(rs_ * nx_[4], rs_ * nx_[5]); p3_ = pk2(rs_ * nx_[6], rs_);    \
            } else { p0_ = pk2(nst_.y, 1.f); p1_ = 0; p2_ = 0; p3_ = 0; }               \
            *(uint4*)&SZW[smt][skk8][sm][0] = (uint4){p0_, p1_, p2_, p3_};              \
        }                                                                               \
        __syncthreads();                                                                \
    }

#pragma unroll 1
    for (int t = 0; t < T; t += 2) {
        L1_STEP(t, s_zA, s_zB, s_hB, s_hA)        // even t: read z A / h B, write h A
        L1_STEP(t + 1, s_zB, s_zA, s_hA, s_hB)    // odd t: roles swapped
    }
#undef L1_STEP
#undef L1_CH
    {  // epilogue: h(T-1) was written at odd parity -> s_hB
        const int ftile = tid >> 8, finner = tid & 255;
        const int efm = finner & 15, efkk8 = finner >> 4;
        const uint4 hv = *(const uint4*)&s_hB[ftile][(efkk8 * 16 + efm) * 8];
        *(uint4*)(hs + ((size_t)(b0 + ftile * 16 + efm) * T + (T - 1)) * 128 + efkk8 * 8) = hv;
    }
}

// ---------------------------------------------------------------------------
// Layer-2 LSTM (R1 structure). R8: bias moved into the MFMA C-init (binit
// splat per gate) -> no bias adds in the gate; launch_bounds (512,1) to
// allow the +16 VGPR (occupancy is grid-pinned at 1 block/CU anyway).
// ---------------------------------------------------------------------------
__global__ __launch_bounds__(512, 1) void lstm_rec_l2(
    const float* __restrict__ Wih, const float* __restrict__ Whh,
    const float* __restrict__ bih, const float* __restrict__ bhh,
    const u16* __restrict__ xin, u16* __restrict__ hlast) {
    __shared__ __align__(16) u16 s_xA[2][16 * 128];
    __shared__ __align__(16) u16 s_xB[2][16 * 128];
    __shared__ __align__(16) u16 s_hA[2][16 * 128];
    __shared__ __align__(16) u16 s_hB[2][16 * 128];

    const int tid = threadIdx.x;
    const int wave = tid >> 6, lane = tid & 63, quad = lane >> 4, n16 = lane & 15;
    const int b0 = blockIdx.x * 32;

    for (int i = tid; i < 2 * 16 * 128; i += 512) ((u16*)s_hB)[i] = 0;

    bf16x8 bWih[4][4], bWhh[4][4];
    f32x4 binit[4];
#pragma unroll
    for (int g = 0; g < 4; ++g) {
        const float sg = (g == 2) ? KG : KS;
        const int wrow = g * 128 + 16 * wave + n16;
        const float bv = (bih[wrow] + bhh[wrow]) * sg;
        binit[g] = (f32x4){bv, bv, bv, bv};
#pragma unroll
        for (int kk = 0; kk < 4; ++kk) {
            const float* pi = Wih + (long)wrow * 128 + kk * 32 + quad * 8;
            const float* ph = Whh + (long)wrow * 128 + kk * 32 + quad * 8;
            bf16x8 bi, bh;
#pragma unroll
            for (int j = 0; j < 8; ++j) { bi[j] = (__bf16)(pi[j] * sg); bh[j] = (__bf16)(ph[j] * sg); }
            bWih[g][kk] = bi; bWhh[g][kk] = bh;
        }
    }

    f32x4 accA[4], accB[4];
    float c[2][4];
#pragma unroll
    for (int mt = 0; mt < 2; ++mt)
#pragma unroll
        for (int r = 0; r < 4; ++r) c[mt][r] = 0.f;

    const int stile = tid >> 8, sinner = tid & 255;
    const int ssm = sinner & 15, sskk8 = sinner >> 4;
    const u16* gsrc = xin + (size_t)(b0 + stile * 16 + ssm) * T * 128 + sskk8 * 8;
    const int soff = sinner * 8;

    const int hwbase = (2 * wave + (n16 >> 3)) * 128 + quad * 32 + (n16 & 7);

    {  // prologue stage x(0) -> xA
        const uint4 v = *(const uint4*)gsrc;
        *(uint4*)&s_xA[stile][soff] = v;
    }
    __syncthreads();

#define L2_CH(AX, AH, G, OUT)                                                           \
    {                                                                                   \
        f32x4 a_ = __builtin_amdgcn_mfma_f32_16x16x32_bf16(AX[0], bWih[G][0], binit[G], 0, 0, 0); \
        a_ = __builtin_amdgcn_mfma_f32_16x16x32_bf16(AH[0], bWhh[G][0], a_, 0, 0, 0);   \
        a_ = __builtin_amdgcn_mfma_f32_16x16x32_bf16(AX[1], bWih[G][1], a_, 0, 0, 0);   \
        a_ = __builtin_amdgcn_mfma_f32_16x16x32_bf16(AH[1], bWhh[G][1], a_, 0, 0, 0);   \
        a_ = __builtin_amdgcn_mfma_f32_16x16x32_bf16(AX[2], bWih[G][2], a_, 0, 0, 0);   \
        a_ = __builtin_amdgcn_mfma_f32_16x16x32_bf16(AH[2], bWhh[G][2], a_, 0, 0, 0);   \
        a_ = __builtin_amdgcn_mfma_f32_16x16x32_bf16(AX[3], bWih[G][3], a_, 0, 0, 0);   \
        a_ = __builtin_amdgcn_mfma_f32_16x16x32_bf16(AH[3], bWhh[G][3], a_, 0, 0, 0);   \
        OUT = a_;                                                                       \
    }

#define L2_STEP(TT, SXR, SXW, SHR, SHW)                                                 \
    {                                                                                   \
        const int t_ = (TT);                                                            \
        const bool hasPre = (t_ + 1 < T);                                               \
        uint4 pre = {};                                                                 \
        if (hasPre) pre = *(const uint4*)(gsrc + (size_t)(t_ + 1) * 128);               \
        bf16x8 aln0[4], ah0[4];                                                         \
        _Pragma("unroll") for (int kk = 0; kk < 4; ++kk) {                              \
            const int ro = (kk * 4 + quad) * 128 + n16 * 8;                             \
            aln0[kk] = *(const bf16x8*)&SXR[0][ro];                                     \
            ah0[kk] = *(const bf16x8*)&SHR[0][ro];                                      \
        }                                                                               \
        f32x4 acc0[4], acc1[4];                                                         \
        L2_CH(aln0, ah0, 0, acc0[0])                                                    \
        L2_CH(aln0, ah0, 1, acc0[1])                                                    \
        L2_CH(aln0, ah0, 2, acc0[2])                                                    \
        L2_CH(aln0, ah0, 3, acc0[3])                                                    \
        bf16x8 aln1[4], ah1[4];                                                         \
        _Pragma("unroll") for (int kk = 0; kk < 4; ++kk) {                              \
            const int ro = (kk * 4 + quad) * 128 + n16 * 8;                             \
            aln1[kk] = *(const bf16x8*)&SXR[1][ro];                                     \
            ah1[kk] = *(const bf16x8*)&SHR[1][ro];                                      \
        }                                                                               \
        L2_CH(aln1, ah1, 0, acc1[0])                                                    \
        GATE_R(acc0, c[0], SHW[0], 0)                                                   \
        L2_CH(aln1, ah1, 1, acc1[1])                                                    \
        GATE_R(acc0, c[0], SHW[0], 1)                                                   \
        L2_CH(aln1, ah1, 2, acc1[2])                                                    \
        GATE_R(acc0, c[0], SHW[0], 2)                                                   \
        L2_CH(aln1, ah1, 3, acc1[3])                                                    \
        GATE_R(acc0, c[0], SHW[0], 3)                                                   \
        GATE_R(acc1, c[1], SHW[1], 0)                                                   \
        GATE_R(acc1, c[1], SHW[1], 1)                                                   \
        GATE_R(acc1, c[1], SHW[1], 2)                                                   \
        GATE_R(acc1, c[1], SHW[1], 3)                                                   \
        if (hasPre) *(uint4*)&SXW[stile][soff] = pre;                                   \
        __syncthreads();                                                                \
    }

#pragma unroll 1
    for (int t = 0; t < T; t += 2) {
        L2_STEP(t, s_xA, s_xB, s_hB, s_hA)        // even t
        L2_STEP(t + 1, s_xB, s_xA, s_hA, s_hB)    // odd t
    }
#undef L2_STEP
#undef L2_CH
    {  // h(T-1) written at odd parity -> s_hB
        const uint4 hv = *(const uint4*)&s_hB[stile][(sskk8 * 16 + ssm) * 8];
        *(uint4*)(hlast + (size_t)(b0 + stile * 16 + ssm) * 128 + sskk8 * 8) = hv;
    }
}

// ---------------------------------------------------------------------------
// Head: 4 rows per wave, 16 rows per block, grid 512. (unchanged)
// ---------------------------------------------------------------------------
__global__ __launch_bounds__(256) void dense_head(
    const u16* __restrict__ hlast, const float* __restrict__ g_ln,
    const float* __restrict__ be_ln, const float* __restrict__ W_d1,
    const float* __restrict__ b_d1, const float* __restrict__ W_d2,
    const float* __restrict__ b_d2, const float* __restrict__ W_d3,
    const float* __restrict__ b_d3, float* __restrict__ out) {
    __shared__ float s_ln[16][128];
    __shared__ float s_d1[16][128];
    __shared__ float s_d2[16][64];
    const int wave = threadIdx.x >> 6, lane = threadIdx.x & 63;
    const long base = (long)blockIdx.x * 16;
    const int R = wave * 4;

#pragma unroll
    for (int rr = 0; rr < 4; ++rr) {
        const long row = base + R + rr;
        const u32 packed = ((const u32*)hlast)[row * 64 + lane];
        float v0 = bfbits2f(packed & 0xffffu), v1 = bfbits2f(packed >> 16);
        const float s = wave_sum(v0 + v1);
        const float q = wave_sum(v0 * v0 + v1 * v1);
        const float mu = s * (1.f / 128.f);
        const float rstd = frsq(q * (1.f / 128.f) - mu * mu + 1e-5f);
        const int h0 = 2 * lane;
        s_ln[R + rr][h0] = (v0 - mu) * rstd * g_ln[h0] + be_ln[h0];
        s_ln[R + rr][h0 + 1] = (v1 - mu) * rstd * g_ln[h0 + 1] + be_ln[h0 + 1];
    }
    __syncthreads();

#pragma unroll
    for (int half = 0; half < 2; ++half) {
        const int o = lane + 64 * half;
        float a[4] = {b_d1[o], b_d1[o], b_d1[o], b_d1[o]};
        const float4* wr = (const float4*)(W_d1 + (long)o * 128);
#pragma unroll 8
        for (int k = 0; k < 32; ++k) {
            const float4 wv = wr[k];
#pragma unroll
            for (int rr = 0; rr < 4; ++rr) {
                const float4 xv = ((const float4*)s_ln[R + rr])[k];
                a[rr] += wv.x * xv.x + wv.y * xv.y + wv.z * xv.z + wv.w * xv.w;
            }
        }
#pragma unroll
        for (int rr = 0; rr < 4; ++rr) s_d1[R + rr][o] = fmaxf(a[rr], 0.f);
    }
    __syncthreads();

    {
        float a[4] = {b_d2[lane], b_d2[lane], b_d2[lane], b_d2[lane]};
        const float4* wr = (const float4*)(W_d2 + (long)lane * 128);
#pragma unroll 8
        for (int k = 0; k < 32; ++k) {
            const float4 wv = wr[k];
#pragma unroll
            for (int rr = 0; rr < 4; ++rr) {
                const float4 xv = ((const float4*)s_d1[R + rr])[k];
                a[rr] += wv.x * xv.x + wv.y * xv.y + wv.z * xv.z + wv.w * xv.w;
            }
        }
#pragma unroll
        for (int rr = 0; rr < 4; ++rr) s_d2[R + rr][lane] = fmaxf(a[rr], 0.f);
    }
    __syncthreads();

    if (lane < NOUT) {
        float a[4] = {b_d3[lane], b_d3[lane], b_d3[lane], b_d3[lane]};
        const float4* wr = (const float4*)(W_d3 + (long)lane * 64);
#pragma unroll
        for (int k = 0; k < 16; ++k) {
            const float4 wv = wr[k];
#pragma unroll
            for (int rr = 0; rr < 4; ++rr) {
                const float4 xv = ((const float4*)s_d2[R + rr])[k];
                a[rr] += wv.x * xv.x + wv.y * xv.y + wv.z * xv.z + wv.w * xv.w;
            }
        }
#pragma unroll
        for (int rr = 0; rr < 4; ++rr) out[(base + R + rr) * NOUT + lane] = a[rr];
    }
}

// ---------------------------------------------------------------------------
extern "C" void kernel_launch(void* const* d_in, const int* in_sizes, int n_in,
                              void* d_out, int out_size, void* d_ws, size_t ws_size,
                              hipStream_t stream) {
    const float* x = (const float*)d_in[0];
    const float* W_in = (const float*)d_in[1];
    const float* b_in = (const float*)d_in[2];
    const float* g_in = (const float*)d_in[3];
    const float* be_in = (const float*)d_in[4];
    const float* Wih0 = (const float*)d_in[5];
    const float* Whh0 = (const float*)d_in[6];
    const float* bih0 = (const float*)d_in[7];
    const float* bhh0 = (const float*)d_in[8];
    const float* Wih1 = (const float*)d_in[9];
    const float* Whh1 = (const float*)d_in[10];
    const float* bih1 = (const float*)d_in[11];
    const float* bhh1 = (const float*)d_in[12];
    const float* g_ln = (const float*)d_in[13];
    const float* be_ln = (const float*)d_in[14];
    const float* W_d1 = (const float*)d_in[15];
    const float* b_d1 = (const float*)d_in[16];
    const float* W_d2 = (const float*)d_in[17];
    const float* b_d2 = (const float*)d_in[18];
    const float* W_d3 = (const float*)d_in[19];
    const float* b_d3 = (const float*)d_in[20];
    float* out = (float*)d_out;

    // workspace layout (~197 MB): aux | Uhat | stats | hs0 | hlast
    char* w = (char*)d_ws;
    float* aux = (float*)w;               w += 512;
    u16* Uhat = (u16*)w;                  w += 512 * 32 * sizeof(u16);
    float2* stats = (float2*)w;           w += (size_t)B * T * sizeof(float2);
    u16* hs0 = (u16*)w;                   w += (size_t)B * T * H * sizeof(u16);
    u16* hlast = (u16*)w;

    prep_aux<<<1, 512, 0, stream>>>(W_in, b_in, g_in, be_in, Wih0, bih0, bhh0, aux, Uhat);
    prep_stats<<<(B * T) / 256, 256, 0, stream>>>(x, aux, stats);
    lstm_rec_l1<<<B / 32, 512, 0, stream>>>(x, stats, Uhat, Whh0, hs0);
    lstm_rec_l2<<<B / 32, 512, 0, stream>>>(Wih1, Whh1, bih1, bhh1, hs0, hlast);
    dense_head<<<B / 16, 256, 0, stream>>>(hlast, g_ln, be_ln, W_d1, b_d1, W_d2, b_d2,
                                           W_d3, b_d3, out);
}